// Round 6
// baseline (2932.088 us; speedup 1.0000x reference)
//
#include <hip/hip_runtime.h>
#include <stdint.h>

#define Tsz 512
#define Dsz 256
#define NCYC 516      // depth 5: van(t=n) l1(n-1) l2(n-2) gx(n-3) gru(n-4)
#define GR 16         // batch rows per block
#define P_X 264       // LDS pitches (f16 units), +8 pad -> 2-way bank alias (free)
#define P_H1 104
#define P_H2 136
#define P_H3 72

typedef _Float16 f16x8 __attribute__((ext_vector_type(8)));
typedef float f32x4 __attribute__((ext_vector_type(4)));

union UHp { uint32_t u; _Float16 s[2]; };
__device__ __forceinline__ uint32_t packh2(float a, float b) {
    UHp x; x.s[0] = (_Float16)a; x.s[1] = (_Float16)b; return x.u;
}
__device__ __forceinline__ float fsig(float x)  { return 1.0f / (1.0f + __expf(-x)); }
__device__ __forceinline__ float ftanh(float x) { return 2.0f / (1.0f + __expf(-2.0f * x)) - 1.0f; }

#define MM(A, B, C) __builtin_amdgcn_mfma_f32_16x16x32_f16((A), (B), (C), 0, 0, 0)

// B-fragment gather: lane holds B[k0 + j][col], j=0..7 (k0 = kt*32 + (lane>>4)*8)
__device__ __forceinline__ f16x8 bfrag(const float* W, int ldw, int k0, int col) {
    f16x8 b;
#pragma unroll
    for (int j = 0; j < 8; ++j) b[j] = (_Float16)W[(size_t)(k0 + j) * ldw + col];
    return b;
}

// 4x4 transpose within lane-quads + pack to 4 f16.
__device__ __forceinline__ uint2 xpose4(float v0, float v1, float v2, float v3, int e) {
    const bool o1 = e & 1;
    float t1 = __shfl_xor(o1 ? v0 : v1, 1);
    float t3 = __shfl_xor(o1 ? v2 : v3, 1);
    if (o1) { v0 = t1; v2 = t3; } else { v1 = t1; v3 = t3; }
    const bool o2 = e & 2;
    float t2 = __shfl_xor(o2 ? v0 : v2, 2);
    float t4 = __shfl_xor(o2 ? v1 : v3, 2);
    if (o2) { v0 = t2; v1 = t4; } else { v2 = t2; v3 = t4; }
    uint2 r; r.x = packh2(v0, v1); r.y = packh2(v2, v3);
    return r;
}

// Block = 16 batch rows, 512 threads = 8 waves, grid 32.
//  w0: van   w1,w2: lstm1   w3,w4: lstm2   w5: gru gx
//  w6: gru recurrent (wave-sync internal zr->a)  w7: pixel fetch+convert
// NOTE: weights live in VGPRs (wfr). launch_bounds MUST keep the VGPR cap high
// enough (512,1 -> 512 regs); (512,2) capped at 128 and spilled wfr to scratch
// (round-5 regression: 861 -> 2926 us).
__global__ __launch_bounds__(512, 1) void rnn_mfma(
    const float* __restrict__ pix,
    const float* __restrict__ van_wi, const float* __restrict__ van_bi,
    const float* __restrict__ van_wh, const float* __restrict__ van_bh,
    const float* __restrict__ w1g, const float* __restrict__ b1g,
    const float* __restrict__ w2g, const float* __restrict__ b2g,
    const float* __restrict__ gwi, const float* __restrict__ gwh,
    const float* __restrict__ gb,
    const float* __restrict__ mw1, const float* __restrict__ mb1,
    const float* __restrict__ mw2, const float* __restrict__ mb2,
    const float* __restrict__ mw3, const float* __restrict__ mb3,
    const float* __restrict__ sf,
    float* __restrict__ out)
{
    const int tid  = threadIdx.x;
    const int wv   = tid >> 6;
    const int lane = tid & 63;
    const int gr0  = blockIdx.x * GR;

    const int rw  = lane & 15;          // A-frag row
    const int kg8 = (lane >> 4) * 8;    // A/B-frag k-group base
    const int c16 = lane & 15;          // B/C col within tile
    const int g   = lane >> 4;          // C row-group
    const int e   = lane & 3;           // quad element
    const int q   = (lane >> 2) & 3;    // quad index
    const int rw7 = lane >> 2, ch = lane & 3;   // pixel wave mapping

    __shared__ __align__(16) _Float16 xls[2][GR * P_X];
    __shared__ __align__(16) _Float16 hc1[2][GR * P_H1];   // [h0(0:32)|h1(32:96)]
    __shared__ __align__(16) _Float16 hc2[2][GR * P_H2];   // [h1(0:64)|h2(64:128)]
    __shared__ __align__(16) float    gxf[2][12 * 256];    // raw gx C-frags
    __shared__ __align__(16) _Float16 h3A[GR * P_H3];      // gru-private (wave-sync)
    __shared__ __align__(16) _Float16 rhA[GR * P_H3];
    __shared__ float sHf[GR][64];
    __shared__ float sT[GR][64];
    __shared__ float sP[GR][12];

    f16x8 wfr[32];            // role-unioned B-fragments (max: lstm2 = 32)
    float bs[12];             // role biases
    float st[16];             // cross-iter state: lstm c (8) / gru h3 (16)
    float4 px[16];            // pixel prefetch regs (w7 only)
#pragma unroll
    for (int i = 0; i < 12; ++i) bs[i] = 0.f;
#pragma unroll
    for (int i = 0; i < 16; ++i) st[i] = 0.f;

    const float* pbase = pix + ((size_t)(gr0 + rw7) * Tsz) * Dsz + ch * 64;

    // ---------------- per-role weight load (once) ----------------
    if (wv == 0) {                       // van: x@wvi + h0@wvh + b
#pragma unroll
        for (int nt = 0; nt < 2; ++nt) {
#pragma unroll
            for (int kt = 0; kt < 8; ++kt)
                wfr[nt * 8 + kt] = bfrag(van_wi, 32, kt * 32 + kg8, nt * 16 + c16);
            wfr[16 + nt] = bfrag(van_wh, 32, kg8, nt * 16 + c16);
            bs[nt] = van_bi[nt * 16 + c16] + van_bh[nt * 16 + c16];
        }
    } else if (wv <= 2) {                // lstm1: K=96
        const int uh = wv - 1;
#pragma unroll
        for (int lu = 0; lu < 2; ++lu) {
            const int ut = 2 * uh + lu;
#pragma unroll
            for (int gt = 0; gt < 4; ++gt) {
#pragma unroll
                for (int kt = 0; kt < 3; ++kt)
                    wfr[lu * 12 + gt * 3 + kt] =
                        bfrag(w1g, 256, kt * 32 + kg8, gt * 64 + ut * 16 + c16);
                bs[lu * 4 + gt] = b1g[gt * 64 + ut * 16 + c16];
            }
        }
    } else if (wv <= 4) {                // lstm2: K=128
        const int uh = wv - 3;
#pragma unroll
        for (int lu = 0; lu < 2; ++lu) {
            const int ut = 2 * uh + lu;
#pragma unroll
            for (int gt = 0; gt < 4; ++gt) {
#pragma unroll
                for (int kt = 0; kt < 4; ++kt)
                    wfr[lu * 16 + gt * 4 + kt] =
                        bfrag(w2g, 256, kt * 32 + kg8, gt * 64 + ut * 16 + c16);
                bs[lu * 4 + gt] = b2g[gt * 64 + ut * 16 + c16];
            }
        }
    } else if (wv == 5) {                // gx: h2 @ gru_wi + gb
#pragma unroll
        for (int t12 = 0; t12 < 12; ++t12) {
#pragma unroll
            for (int kt = 0; kt < 2; ++kt)
                wfr[t12 * 2 + kt] = bfrag(gwi, 192, kt * 32 + kg8, t12 * 16 + c16);
            bs[t12] = gb[t12 * 16 + c16];
        }
    } else if (wv == 6) {                // gru recurrent: gwh z / r / a
#pragma unroll
        for (int j = 0; j < 4; ++j) {
#pragma unroll
            for (int kt = 0; kt < 2; ++kt) {
                wfr[j * 2 + kt]      = bfrag(gwh, 192, kt * 32 + kg8, j * 16 + c16);
                wfr[8 + j * 2 + kt]  = bfrag(gwh, 192, kt * 32 + kg8, 64 + j * 16 + c16);
                wfr[16 + j * 2 + kt] = bfrag(gwh, 192, kt * 32 + kg8, 128 + j * 16 + c16);
            }
        }
    } else {                             // w7: pixel prologue
#pragma unroll
        for (int m = 0; m < 16; ++m) px[m] = ((const float4*)pbase)[m];
        uint4* dst = (uint4*)(xls[1] + rw7 * P_X + ch * 64);
#pragma unroll
        for (int m = 0; m < 8; ++m) {
            uint4 w;
            w.x = packh2(px[2 * m].x, px[2 * m].y);
            w.y = packh2(px[2 * m].z, px[2 * m].w);
            w.z = packh2(px[2 * m + 1].x, px[2 * m + 1].y);
            w.w = packh2(px[2 * m + 1].z, px[2 * m + 1].w);
            dst[m] = w;
        }
#pragma unroll
        for (int m = 0; m < 16; ++m) px[m] = ((const float4*)(pbase + Dsz))[m];
    }

    for (int i = tid; i < 2 * GR * P_H1; i += 512) ((_Float16*)hc1)[i] = (_Float16)0.f;
    for (int i = tid; i < 2 * GR * P_H2; i += 512) ((_Float16*)hc2)[i] = (_Float16)0.f;
    for (int i = tid; i < GR * P_H3; i += 512) h3A[i] = (_Float16)0.f;
    __syncthreads();

    // ---------------- pipelined recurrence ----------------
    for (int n = 0; n < NCYC; ++n) {
        const int wb = n & 1, rb = wb ^ 1;

        if (wv == 0) {
            if (n < Tsz) {
                f16x8 Ax[8];
#pragma unroll
                for (int kt = 0; kt < 8; ++kt)
                    Ax[kt] = *(const f16x8*)(xls[rb] + rw * P_X + kt * 32 + kg8);
                f16x8 Ah = *(const f16x8*)(hc1[rb] + rw * P_H1 + kg8);
#pragma unroll
                for (int nt = 0; nt < 2; ++nt) {
                    // two independent accumulation chains, summed at the end
                    f32x4 C0 = {bs[nt], bs[nt], bs[nt], bs[nt]};
                    f32x4 C1 = {0.f, 0.f, 0.f, 0.f};
#pragma unroll
                    for (int kt = 0; kt < 4; ++kt) C0 = MM(Ax[kt], wfr[nt * 8 + kt], C0);
#pragma unroll
                    for (int kt = 4; kt < 8; ++kt) C1 = MM(Ax[kt], wfr[nt * 8 + kt], C1);
                    C1 = MM(Ah, wfr[16 + nt], C1);
                    uint2 rpk = xpose4(fmaxf(C0[0] + C1[0], 0.f), fmaxf(C0[1] + C1[1], 0.f),
                                       fmaxf(C0[2] + C1[2], 0.f), fmaxf(C0[3] + C1[3], 0.f), e);
                    *(uint2*)(hc1[wb] + (g * 4 + e) * P_H1 + nt * 16 + 4 * q) = rpk;
                }
            }
        } else if (wv <= 2) {
            const int t = n - 1;
            if (0 <= t && t < Tsz) {
                f16x8 A1[3];
#pragma unroll
                for (int kt = 0; kt < 3; ++kt)
                    A1[kt] = *(const f16x8*)(hc1[rb] + rw * P_H1 + kt * 32 + kg8);
#pragma unroll
                for (int lu = 0; lu < 2; ++lu) {
                    const int ut = 2 * (wv - 1) + lu;
                    f32x4 Ci = {bs[lu*4+0], bs[lu*4+0], bs[lu*4+0], bs[lu*4+0]};
                    f32x4 Cg = {bs[lu*4+1], bs[lu*4+1], bs[lu*4+1], bs[lu*4+1]};
                    f32x4 Cf = {bs[lu*4+2], bs[lu*4+2], bs[lu*4+2], bs[lu*4+2]};
                    f32x4 Co = {bs[lu*4+3], bs[lu*4+3], bs[lu*4+3], bs[lu*4+3]};
#pragma unroll
                    for (int kt = 0; kt < 3; ++kt) {
                        Ci = MM(A1[kt], wfr[lu * 12 + 0 + kt], Ci);
                        Cg = MM(A1[kt], wfr[lu * 12 + 3 + kt], Cg);
                        Cf = MM(A1[kt], wfr[lu * 12 + 6 + kt], Cf);
                        Co = MM(A1[kt], wfr[lu * 12 + 9 + kt], Co);
                    }
                    float hv[4];
#pragma unroll
                    for (int p = 0; p < 4; ++p) {
                        float cc = fsig(Cf[p] + 1.f) * st[lu * 4 + p]
                                 + fsig(Ci[p]) * ftanh(Cg[p]);
                        st[lu * 4 + p] = cc;
                        hv[p] = fsig(Co[p]) * ftanh(cc);
                    }
                    uint2 rpk = xpose4(hv[0], hv[1], hv[2], hv[3], e);
                    *(uint2*)(hc1[wb] + (g * 4 + e) * P_H1 + 32 + ut * 16 + 4 * q) = rpk;
                    *(uint2*)(hc2[wb] + (g * 4 + e) * P_H2 + ut * 16 + 4 * q) = rpk;
                }
            }
        } else if (wv <= 4) {
            const int t = n - 2;
            if (0 <= t && t < Tsz) {
                f16x8 A2[4];
#pragma unroll
                for (int kt = 0; kt < 4; ++kt)
                    A2[kt] = *(const f16x8*)(hc2[rb] + rw * P_H2 + kt * 32 + kg8);
#pragma unroll
                for (int lu = 0; lu < 2; ++lu) {
                    const int ut = 2 * (wv - 3) + lu;
                    f32x4 Ci = {bs[lu*4+0], bs[lu*4+0], bs[lu*4+0], bs[lu*4+0]};
                    f32x4 Cg = {bs[lu*4+1], bs[lu*4+1], bs[lu*4+1], bs[lu*4+1]};
                    f32x4 Cf = {bs[lu*4+2], bs[lu*4+2], bs[lu*4+2], bs[lu*4+2]};
                    f32x4 Co = {bs[lu*4+3], bs[lu*4+3], bs[lu*4+3], bs[lu*4+3]};
#pragma unroll
                    for (int kt = 0; kt < 4; ++kt) {
                        Ci = MM(A2[kt], wfr[lu * 16 + 0 + kt], Ci);
                        Cg = MM(A2[kt], wfr[lu * 16 + 4 + kt], Cg);
                        Cf = MM(A2[kt], wfr[lu * 16 + 8 + kt], Cf);
                        Co = MM(A2[kt], wfr[lu * 16 + 12 + kt], Co);
                    }
                    float hv[4];
#pragma unroll
                    for (int p = 0; p < 4; ++p) {
                        float cc = fsig(Cf[p] + 1.f) * st[lu * 4 + p]
                                 + fsig(Ci[p]) * ftanh(Cg[p]);
                        st[lu * 4 + p] = cc;
                        hv[p] = fsig(Co[p]) * ftanh(cc);
                    }
                    uint2 rpk = xpose4(hv[0], hv[1], hv[2], hv[3], e);
                    *(uint2*)(hc2[wb] + (g * 4 + e) * P_H2 + 64 + ut * 16 + 4 * q) = rpk;
                }
            }
        } else if (wv == 5) {
            const int t = n - 3;
            if (0 <= t && t < Tsz) {
                f16x8 Ag[2];
#pragma unroll
                for (int kt = 0; kt < 2; ++kt)
                    Ag[kt] = *(const f16x8*)(hc2[rb] + rw * P_H2 + 64 + kt * 32 + kg8);
#pragma unroll
                for (int t12 = 0; t12 < 12; ++t12) {
                    f32x4 C = {bs[t12], bs[t12], bs[t12], bs[t12]};
                    C = MM(Ag[0], wfr[t12 * 2 + 0], C);
                    C = MM(Ag[1], wfr[t12 * 2 + 1], C);
                    *(f32x4*)(gxf[wb] + t12 * 256 + lane * 4) = C;
                }
            }
        } else if (wv == 6) {
            const int t = n - 4;
            if (0 <= t && t < Tsz) {
                f16x8 Ah[2];
#pragma unroll
                for (int kt = 0; kt < 2; ++kt)
                    Ah[kt] = *(const f16x8*)(h3A + rw * P_H3 + kt * 32 + kg8);
                float z_[16];
#pragma unroll
                for (int j = 0; j < 4; ++j) {
                    f32x4 Cz = *(const f32x4*)(gxf[rb] + j * 256 + lane * 4);
                    f32x4 Cr = *(const f32x4*)(gxf[rb] + (4 + j) * 256 + lane * 4);
#pragma unroll
                    for (int kt = 0; kt < 2; ++kt) {
                        Cz = MM(Ah[kt], wfr[j * 2 + kt], Cz);
                        Cr = MM(Ah[kt], wfr[8 + j * 2 + kt], Cr);
                    }
                    float rh[4];
#pragma unroll
                    for (int p = 0; p < 4; ++p) {
                        z_[j * 4 + p] = fsig(Cz[p]);
                        rh[p] = fsig(Cr[p]) * st[j * 4 + p];
                    }
                    uint2 rpk = xpose4(rh[0], rh[1], rh[2], rh[3], e);
                    *(uint2*)(rhA + (g * 4 + e) * P_H3 + j * 16 + 4 * q) = rpk;
                }
                asm volatile("s_waitcnt lgkmcnt(0)" ::: "memory");
                __builtin_amdgcn_sched_barrier(0);
                f16x8 Ar[2];
#pragma unroll
                for (int kt = 0; kt < 2; ++kt)
                    Ar[kt] = *(const f16x8*)(rhA + rw * P_H3 + kt * 32 + kg8);
#pragma unroll
                for (int j = 0; j < 4; ++j) {
                    f32x4 Ca = *(const f32x4*)(gxf[rb] + (8 + j) * 256 + lane * 4);
                    Ca = MM(Ar[0], wfr[16 + j * 2 + 0], Ca);
                    Ca = MM(Ar[1], wfr[16 + j * 2 + 1], Ca);
                    float hn[4];
#pragma unroll
                    for (int p = 0; p < 4; ++p) {
                        float av = ftanh(Ca[p]);
                        float z  = z_[j * 4 + p];
                        float h  = st[j * 4 + p];
                        h = (1.f - z) * h + z * av;
                        st[j * 4 + p] = h;
                        hn[p] = h;
                    }
                    uint2 rpk = xpose4(hn[0], hn[1], hn[2], hn[3], e);
                    *(uint2*)(h3A + (g * 4 + e) * P_H3 + j * 16 + 4 * q) = rpk;
                }
            }
        } else {
            if (n + 1 < Tsz) {
                uint4* dst = (uint4*)(xls[wb] + rw7 * P_X + ch * 64);
#pragma unroll
                for (int m = 0; m < 8; ++m) {
                    uint4 w;
                    w.x = packh2(px[2 * m].x, px[2 * m].y);
                    w.y = packh2(px[2 * m].z, px[2 * m].w);
                    w.z = packh2(px[2 * m + 1].x, px[2 * m + 1].y);
                    w.w = packh2(px[2 * m + 1].z, px[2 * m + 1].w);
                    dst[m] = w;
                }
            }
            if (n + 2 < Tsz) {
                const float4* src = (const float4*)(pbase + (size_t)(n + 2) * Dsz);
#pragma unroll
                for (int m = 0; m < 16; ++m) px[m] = src[m];
            }
        }
        __syncthreads();
    }

    // ---------------- MLP head (16 rows) ----------------
    if (wv == 6) {
#pragma unroll
        for (int j = 0; j < 4; ++j)
#pragma unroll
            for (int p = 0; p < 4; ++p)
                sHf[g * 4 + p][j * 16 + c16] = st[j * 4 + p];
    }
    __syncthreads();
    {
        const int hr = tid >> 5, hcx = tid & 31;
        float acc = mb1[hcx];
#pragma unroll
        for (int k = 0; k < 64; ++k) acc = fmaf(sHf[hr][k], mw1[k * 32 + hcx], acc);
        sT[hr][hcx] = fmaxf(acc, 0.f);
    }
    __syncthreads();
    {
        const int hr = tid >> 5, hcx = tid & 31;
        float acc = mb2[hcx];
#pragma unroll
        for (int k = 0; k < 32; ++k) acc = fmaf(sT[hr][k], mw2[k * 32 + hcx], acc);
        sT[hr][32 + hcx] = fmaxf(acc, 0.f);
    }
    __syncthreads();
    if (tid < 192) {
        const int hr = tid / 12, c = tid - 12 * hr;
        float acc = mb3[c];
#pragma unroll
        for (int k = 0; k < 32; ++k) acc = fmaf(sT[hr][32 + k], mw3[k * 12 + c], acc);
        sP[hr][c] = acc;
    }
    __syncthreads();
    if (tid < GR) {
        float acc = 0.f;
#pragma unroll
        for (int k = 0; k < 12; ++k) acc = fmaf(sP[tid][k], sf[k], acc);
        out[24 + gr0 + tid] = acc;
    }
    if (blockIdx.x == 0 && tid < 12) {
        out[tid] = sf[tid];
        out[12 + tid] = 1.0f;
    }
}

extern "C" void kernel_launch(void* const* d_in, const int* in_sizes, int n_in,
                              void* d_out, int out_size, void* d_ws, size_t ws_size,
                              hipStream_t stream) {
    (void)in_sizes; (void)n_in; (void)d_ws; (void)ws_size; (void)out_size;
    const float* pix    = (const float*)d_in[0];
    const float* van_wi = (const float*)d_in[1];
    const float* van_bi = (const float*)d_in[2];
    const float* van_wh = (const float*)d_in[3];
    const float* van_bh = (const float*)d_in[4];
    const float* w1     = (const float*)d_in[5];
    const float* b1     = (const float*)d_in[6];
    const float* w2     = (const float*)d_in[7];
    const float* b2     = (const float*)d_in[8];
    const float* gwi    = (const float*)d_in[9];
    const float* gwh    = (const float*)d_in[10];
    const float* gb     = (const float*)d_in[11];
    const float* mw1    = (const float*)d_in[12];
    const float* mb1    = (const float*)d_in[13];
    const float* mw2    = (const float*)d_in[14];
    const float* mb2    = (const float*)d_in[15];
    const float* mw3    = (const float*)d_in[16];
    const float* mb3    = (const float*)d_in[17];
    const float* sf     = (const float*)d_in[18];
    float* out = (float*)d_out;

    rnn_mfma<<<32, 512, 0, stream>>>(
        pix, van_wi, van_bi, van_wh, van_bh,
        w1, b1, w2, b2, gwi, gwh, gb,
        mw1, mb1, mw2, mb2, mw3, mb3, sf, out);
}

// Round 7
// 1036.293 us; speedup vs baseline: 2.8294x; 2.8294x over previous
//
#include <hip/hip_runtime.h>
#include <stdint.h>

#define Tsz 512
#define Dsz 256
#define NCYC 516   // depth 5: van(n) lstm1(n-1) lstm2(n-2) gx(n-3) gru(n-4)

union UHp { uint32_t u; _Float16 s[2]; };
__device__ __forceinline__ uint32_t packh(float a, float b) {
    UHp x; x.s[0] = (_Float16)a; x.s[1] = (_Float16)b; return x.u;
}
__device__ __forceinline__ float dot2(uint32_t w, uint32_t a, float c) {
#if __has_builtin(__builtin_amdgcn_fdot2)
    typedef _Float16 h2 __attribute__((ext_vector_type(2)));
    union U { uint32_t u; h2 h; };
    U W, A; W.u = w; A.u = a;
    return __builtin_amdgcn_fdot2(W.h, A.h, c, false);
#else
    float d;
    asm("v_dot2_f32_f16 %0, %1, %2, %3" : "=v"(d) : "v"(w), "v"(a), "v"(c));
    return d;
#endif
}
__device__ __forceinline__ float fsig(float x)  { return 1.0f / (1.0f + __expf(-x)); }
__device__ __forceinline__ float ftanh(float x) { return 2.0f / (1.0f + __expf(-2.0f * x)) - 1.0f; }

#define D4(ACC, WP, V) \
    do { ACC = dot2((WP)[0], (V).x, ACC); ACC = dot2((WP)[1], (V).y, ACC); \
         ACC = dot2((WP)[2], (V).z, ACC); ACC = dot2((WP)[3], (V).w, ACC); } while (0)

// Block = 2 batch rows, 768 threads = 12 waves (3/SIMD), grid 256 (1 block/CU).
//  wv0    : van (both rows) + pixel prefetch        (72 w-regs)
//  wv1-4  : lstm1, 16 units/wave, lane-quad = i,g,f,o of one unit (48 w-regs)
//  wv5-8  : lstm2, same scheme, k=128               (64 w-regs)
//  wv9-10 : gru gx, one row each, 3 cols/lane       (96 w-regs)
//  wv11   : gru recurrent, both rows (wave-sync internal zr->a)  (96 w-regs)
// Registers: every role <= ~150; 12 waves -> compiler cap ~168. Weights stay
// in VGPRs (the whole design premise) -- do NOT tighten launch_bounds.
__global__ __launch_bounds__(768, 1) void rnn12(
    const float* __restrict__ pix,
    const float* __restrict__ van_wi, const float* __restrict__ van_bi,
    const float* __restrict__ van_wh, const float* __restrict__ van_bh,
    const float* __restrict__ w1g, const float* __restrict__ b1g,
    const float* __restrict__ w2g, const float* __restrict__ b2g,
    const float* __restrict__ gwi, const float* __restrict__ gwh,
    const float* __restrict__ gb,
    const float* __restrict__ mw1, const float* __restrict__ mb1,
    const float* __restrict__ mw2, const float* __restrict__ mb2,
    const float* __restrict__ mw3, const float* __restrict__ mb3,
    const float* __restrict__ sf,
    float* __restrict__ out)
{
    const int tid  = threadIdx.x;
    const int wv   = tid >> 6;
    const int lane = tid & 63;
    const int r0   = 2 * blockIdx.x;

    __shared__ __align__(16) _Float16 xb [2][2][256];  // x(t) f16 [buf][row]
    __shared__ __align__(16) _Float16 hc1[2][2][96];   // [h0(0:32)|h1(32:96)]
    __shared__ __align__(16) _Float16 hc2[2][2][128];  // [h1(0:64)|h2(64:128)]
    __shared__ __align__(16) _Float16 gxb[2][2][192];  // z_x|r_x|a_x
    __shared__ __align__(16) _Float16 h3s[2][64];      // gru-private
    __shared__ __align__(16) _Float16 rh3s[2][64];
    __shared__ float sHf[2][64];
    __shared__ float sT[2][64];
    __shared__ float sP[2][12];

    uint32_t wreg[96];
    float bz0 = 0.f, bz1 = 0.f, bz2 = 0.f;
    float cs0 = 0.f, cs1 = 0.f;          // lstm c-state (lane gate==2) / gru h3
    float4 pxA0{}, pxB0{}, pxA1{}, pxB1{};
    const float* pr0 = nullptr; const float* pr1 = nullptr;

    const int s4   = lane >> 2;          // lstm unit-slot within wave
    const int gate = lane & 3;           // 0:i 1:g 2:f 3:o

    // ---------------- per-role weight load (once) ----------------
    if (wv == 0) {                        // van
        const int c = lane & 31, s = lane >> 5;
#pragma unroll
        for (int j = 0; j < 64; ++j)
            wreg[j] = packh(van_wi[(128 * s + 2 * j) * 32 + c],
                            van_wi[(128 * s + 2 * j + 1) * 32 + c]);
#pragma unroll
        for (int j = 0; j < 8; ++j)
            wreg[64 + j] = packh(van_wh[(16 * s + 2 * j) * 32 + c],
                                 van_wh[(16 * s + 2 * j + 1) * 32 + c]);
        bz0 = van_bi[c] + van_bh[c];
        pr0 = pix + (size_t)r0 * Tsz * Dsz;
        pr1 = pr0 + (size_t)Tsz * Dsz;
        float4 p0 = *(const float4*)(pr0 + 4 * lane);
        float4 p1 = *(const float4*)(pr1 + 4 * lane);
        uint32_t* x0 = (uint32_t*)xb[1][0];
        uint32_t* x1 = (uint32_t*)xb[1][1];
        x0[2 * lane] = packh(p0.x, p0.y); x0[2 * lane + 1] = packh(p0.z, p0.w);
        x1[2 * lane] = packh(p1.x, p1.y); x1[2 * lane + 1] = packh(p1.z, p1.w);
        pxA0 = *(const float4*)(pr0 + Dsz + 4 * lane);
        pxB0 = *(const float4*)(pr0 + 2 * (size_t)Dsz + 4 * lane);
        pxA1 = *(const float4*)(pr1 + Dsz + 4 * lane);
        pxB1 = *(const float4*)(pr1 + 2 * (size_t)Dsz + 4 * lane);
    } else if (wv <= 4) {                 // lstm1: unit u, col = gate*64+u, k=96
        const int u = (wv - 1) * 16 + s4;
        const int col = gate * 64 + u;
#pragma unroll
        for (int j = 0; j < 48; ++j)
            wreg[j] = packh(w1g[(2 * j) * 256 + col], w1g[(2 * j + 1) * 256 + col]);
        bz0 = b1g[col];
    } else if (wv <= 8) {                 // lstm2: k=128
        const int u = (wv - 5) * 16 + s4;
        const int col = gate * 64 + u;
#pragma unroll
        for (int j = 0; j < 64; ++j)
            wreg[j] = packh(w2g[(2 * j) * 256 + col], w2g[(2 * j + 1) * 256 + col]);
        bz0 = b2g[col];
    } else if (wv <= 10) {                // gx: h2 @ gru_wi, one row, 3 cols/lane
#pragma unroll
        for (int j = 0; j < 32; ++j) {
            wreg[j]      = packh(gwi[(2 * j) * 192 + lane],       gwi[(2 * j + 1) * 192 + lane]);
            wreg[32 + j] = packh(gwi[(2 * j) * 192 + 64 + lane],  gwi[(2 * j + 1) * 192 + 64 + lane]);
            wreg[64 + j] = packh(gwi[(2 * j) * 192 + 128 + lane], gwi[(2 * j + 1) * 192 + 128 + lane]);
        }
        bz0 = gb[lane]; bz1 = gb[64 + lane]; bz2 = gb[128 + lane];
    } else {                              // gru recurrent: gwh z|r|a
#pragma unroll
        for (int j = 0; j < 32; ++j) {
            wreg[j]      = packh(gwh[(2 * j) * 192 + lane],       gwh[(2 * j + 1) * 192 + lane]);
            wreg[32 + j] = packh(gwh[(2 * j) * 192 + 64 + lane],  gwh[(2 * j + 1) * 192 + 64 + lane]);
            wreg[64 + j] = packh(gwh[(2 * j) * 192 + 128 + lane], gwh[(2 * j + 1) * 192 + 128 + lane]);
        }
    }

    for (int i = tid; i < 2 * 2 * 96;  i += 768) ((_Float16*)hc1)[i] = (_Float16)0.f;
    for (int i = tid; i < 2 * 2 * 128; i += 768) ((_Float16*)hc2)[i] = (_Float16)0.f;
    for (int i = tid; i < 2 * 64; i += 768) { ((_Float16*)h3s)[i] = (_Float16)0.f; ((_Float16*)rh3s)[i] = (_Float16)0.f; }
    __syncthreads();

    // ---------------- pipelined recurrence ----------------
    for (int n = 0; n < NCYC; ++n) {
        const int wb = n & 1, rb = wb ^ 1;

        if (wv == 0) {
            if (n + 1 < Tsz) {
                uint32_t* x0 = (uint32_t*)xb[wb][0];
                uint32_t* x1 = (uint32_t*)xb[wb][1];
                x0[2 * lane] = packh(pxA0.x, pxA0.y); x0[2 * lane + 1] = packh(pxA0.z, pxA0.w);
                x1[2 * lane] = packh(pxA1.x, pxA1.y); x1[2 * lane + 1] = packh(pxA1.z, pxA1.w);
            }
            pxA0 = pxB0; pxA1 = pxB1;
            if (n + 3 < Tsz) {
                pxB0 = *(const float4*)(pr0 + (size_t)(n + 3) * Dsz + 4 * lane);
                pxB1 = *(const float4*)(pr1 + (size_t)(n + 3) * Dsz + 4 * lane);
            }
            if (n < Tsz) {
                const int c = lane & 31, s = lane >> 5;
#pragma unroll
                for (int r = 0; r < 2; ++r) {
                    const uint4* xq = ((const uint4*)xb[rb][r]) + 16 * s;
                    const uint4* hq = ((const uint4*)hc1[rb][r]) + 2 * s;
                    float a0 = 0.f, a1 = 0.f;
#pragma unroll
                    for (int q = 0; q < 16; q += 2) {
                        uint4 v0 = xq[q], v1 = xq[q + 1];
                        D4(a0, &wreg[4 * q], v0);
                        D4(a1, &wreg[4 * q + 4], v1);
                    }
                    {
                        uint4 v0 = hq[0], v1 = hq[1];
                        D4(a0, &wreg[64], v0);
                        D4(a1, &wreg[68], v1);
                    }
                    float acc = a0 + a1;
                    acc += __shfl_xor(acc, 32);
                    if (s == 0) hc1[wb][r][c] = (_Float16)fmaxf(acc + bz0, 0.f);
                }
            }
        } else if (wv <= 4) {
            const int t = n - 1;
            if (0 <= t && t < Tsz) {
                const int u = (wv - 1) * 16 + s4;
#pragma unroll
                for (int r = 0; r < 2; ++r) {
                    const uint4* aq = (const uint4*)hc1[rb][r];   // 12 uint4
                    float a0 = bz0, a1 = 0.f;
#pragma unroll
                    for (int q = 0; q < 12; q += 2) {
                        uint4 v0 = aq[q], v1 = aq[q + 1];
                        D4(a0, &wreg[4 * q], v0);
                        D4(a1, &wreg[4 * q + 4], v1);
                    }
                    float acc = a0 + a1;
                    // quad combine: gate 0:i 1:g 2:f 3:o
                    float tv;
                    if (gate == 0)      tv = fsig(acc);
                    else if (gate == 1) tv = ftanh(acc);
                    else if (gate == 2) tv = fsig(acc + 1.f);
                    else                tv = fsig(acc);
                    float o1   = __shfl_xor(tv, 1);       // lane0: tg
                    float prod = tv * o1;                 // lane0: sig(i)*tanh(g)
                    float pc   = tv * (r ? cs1 : cs0);    // lane2: sig(f+1)*c
                    float p01  = __shfl_xor(prod, 2);     // lane2 <- lane0 prod
                    float cnew = pc + p01;                // lane2
                    if (gate == 2) { if (r) cs1 = cnew; else cs0 = cnew; }
                    float tc  = ftanh(cnew);              // lane2
                    float tcx = __shfl_xor(tc, 1);        // lane3 <- lane2
                    if (gate == 3) {
                        _Float16 hv = (_Float16)(tv * tcx);
                        hc1[wb][r][32 + u] = hv;
                        hc2[wb][r][u]      = hv;
                    }
                }
            }
        } else if (wv <= 8) {
            const int t = n - 2;
            if (0 <= t && t < Tsz) {
                const int u = (wv - 5) * 16 + s4;
#pragma unroll
                for (int r = 0; r < 2; ++r) {
                    const uint4* aq = (const uint4*)hc2[rb][r];   // 16 uint4
                    float a0 = bz0, a1 = 0.f;
#pragma unroll
                    for (int q = 0; q < 16; q += 2) {
                        uint4 v0 = aq[q], v1 = aq[q + 1];
                        D4(a0, &wreg[4 * q], v0);
                        D4(a1, &wreg[4 * q + 4], v1);
                    }
                    float acc = a0 + a1;
                    float tv;
                    if (gate == 0)      tv = fsig(acc);
                    else if (gate == 1) tv = ftanh(acc);
                    else if (gate == 2) tv = fsig(acc + 1.f);
                    else                tv = fsig(acc);
                    float o1   = __shfl_xor(tv, 1);
                    float prod = tv * o1;
                    float pc   = tv * (r ? cs1 : cs0);
                    float p01  = __shfl_xor(prod, 2);
                    float cnew = pc + p01;
                    if (gate == 2) { if (r) cs1 = cnew; else cs0 = cnew; }
                    float tc  = ftanh(cnew);
                    float tcx = __shfl_xor(tc, 1);
                    if (gate == 3)
                        hc2[wb][r][64 + u] = (_Float16)(tv * tcx);
                }
            }
        } else if (wv <= 10) {
            const int t = n - 3;
            const int r = wv - 9;
            if (0 <= t && t < Tsz) {
                const uint4* hq = (const uint4*)(hc2[rb][r] + 64);  // 8 uint4
                float az = bz0, ar = bz1, aa = bz2;
#pragma unroll
                for (int q = 0; q < 8; ++q) {
                    uint4 v = hq[q];
                    D4(az, &wreg[4 * q], v);
                    D4(ar, &wreg[32 + 4 * q], v);
                    D4(aa, &wreg[64 + 4 * q], v);
                }
                gxb[wb][r][lane]       = (_Float16)az;
                gxb[wb][r][64 + lane]  = (_Float16)ar;
                gxb[wb][r][128 + lane] = (_Float16)aa;
            }
        } else {
            const int t = n - 4;
            if (0 <= t && t < Tsz) {
                float z0, z1, ga0, ga1;
                {   // row 0 z/r
                    const uint4* hq = (const uint4*)h3s[0];
                    float az = (float)gxb[rb][0][lane], ar = (float)gxb[rb][0][64 + lane];
#pragma unroll
                    for (int q = 0; q < 8; ++q) {
                        uint4 v = hq[q];
                        D4(az, &wreg[4 * q], v);
                        D4(ar, &wreg[32 + 4 * q], v);
                    }
                    z0 = fsig(az);
                    rh3s[0][lane] = (_Float16)(fsig(ar) * cs0);
                    ga0 = (float)gxb[rb][0][128 + lane];
                }
                {   // row 1 z/r
                    const uint4* hq = (const uint4*)h3s[1];
                    float az = (float)gxb[rb][1][lane], ar = (float)gxb[rb][1][64 + lane];
#pragma unroll
                    for (int q = 0; q < 8; ++q) {
                        uint4 v = hq[q];
                        D4(az, &wreg[4 * q], v);
                        D4(ar, &wreg[32 + 4 * q], v);
                    }
                    z1 = fsig(az);
                    rh3s[1][lane] = (_Float16)(fsig(ar) * cs1);
                    ga1 = (float)gxb[rb][1][128 + lane];
                }
                asm volatile("s_waitcnt lgkmcnt(0)" ::: "memory");
                __builtin_amdgcn_sched_barrier(0);
                {   // row 0 a + update
                    const uint4* rq = (const uint4*)rh3s[0];
                    float aa = ga0, ab = 0.f;
#pragma unroll
                    for (int q = 0; q < 8; ++q) {
                        uint4 v = rq[q];
                        if (q & 1) { D4(ab, &wreg[64 + 4 * q], v); }
                        else       { D4(aa, &wreg[64 + 4 * q], v); }
                    }
                    float av = ftanh(aa + ab);
                    cs0 = (1.f - z0) * cs0 + z0 * av;
                    h3s[0][lane] = (_Float16)cs0;
                }
                {   // row 1 a + update
                    const uint4* rq = (const uint4*)rh3s[1];
                    float aa = ga1, ab = 0.f;
#pragma unroll
                    for (int q = 0; q < 8; ++q) {
                        uint4 v = rq[q];
                        if (q & 1) { D4(ab, &wreg[64 + 4 * q], v); }
                        else       { D4(aa, &wreg[64 + 4 * q], v); }
                    }
                    float av = ftanh(aa + ab);
                    cs1 = (1.f - z1) * cs1 + z1 * av;
                    h3s[1][lane] = (_Float16)cs1;
                }
            }
        }
        __syncthreads();
    }

    // ---------------- MLP head (2 rows) ----------------
    if (wv == 11) { sHf[0][lane] = cs0; sHf[1][lane] = cs1; }
    __syncthreads();
    if (tid < 64) {
        const int r = tid >> 5, c = tid & 31;
        float acc = mb1[c];
#pragma unroll
        for (int k = 0; k < 64; ++k) acc = fmaf(sHf[r][k], mw1[k * 32 + c], acc);
        sT[r][c] = fmaxf(acc, 0.f);
    }
    __syncthreads();
    if (tid < 64) {
        const int r = tid >> 5, c = tid & 31;
        float acc = mb2[c];
#pragma unroll
        for (int k = 0; k < 32; ++k) acc = fmaf(sT[r][k], mw2[k * 32 + c], acc);
        sT[r][32 + c] = fmaxf(acc, 0.f);
    }
    __syncthreads();
    if (tid < 24) {
        const int r = tid / 12, c = tid - 12 * r;
        float acc = mb3[c];
#pragma unroll
        for (int k = 0; k < 32; ++k) acc = fmaf(sT[r][32 + k], mw3[k * 12 + c], acc);
        sP[r][c] = acc;
    }
    __syncthreads();
    if (tid < 2) {
        float acc = 0.f;
#pragma unroll
        for (int k = 0; k < 12; ++k) acc = fmaf(sP[tid][k], sf[k], acc);
        out[24 + r0 + tid] = acc;
    }
    if (blockIdx.x == 0 && tid < 12) {
        out[tid] = sf[tid];
        out[12 + tid] = 1.0f;
    }
}

extern "C" void kernel_launch(void* const* d_in, const int* in_sizes, int n_in,
                              void* d_out, int out_size, void* d_ws, size_t ws_size,
                              hipStream_t stream) {
    (void)in_sizes; (void)n_in; (void)d_ws; (void)ws_size; (void)out_size;
    const float* pix    = (const float*)d_in[0];
    const float* van_wi = (const float*)d_in[1];
    const float* van_bi = (const float*)d_in[2];
    const float* van_wh = (const float*)d_in[3];
    const float* van_bh = (const float*)d_in[4];
    const float* w1     = (const float*)d_in[5];
    const float* b1     = (const float*)d_in[6];
    const float* w2     = (const float*)d_in[7];
    const float* b2     = (const float*)d_in[8];
    const float* gwi    = (const float*)d_in[9];
    const float* gwh    = (const float*)d_in[10];
    const float* gb     = (const float*)d_in[11];
    const float* mw1    = (const float*)d_in[12];
    const float* mb1    = (const float*)d_in[13];
    const float* mw2    = (const float*)d_in[14];
    const float* mb2    = (const float*)d_in[15];
    const float* mw3    = (const float*)d_in[16];
    const float* mb3    = (const float*)d_in[17];
    const float* sf     = (const float*)d_in[18];
    float* out = (float*)d_out;

    rnn12<<<256, 768, 0, stream>>>(
        pix, van_wi, van_bi, van_wh, van_bh,
        w1, b1, w2, b2, gwi, gwh, gb,
        mw1, mb1, mw2, mb2, mw3, mb3, sf, out);
}

// Round 8
// 852.381 us; speedup vs baseline: 3.4399x; 1.2158x over previous
//
#include <hip/hip_runtime.h>
#include <stdint.h>

#define Tsz 512
#define Dsz 256
#define NCYC (Tsz + 4)   // depth 5: van(t) l1(t-1) l2(t-2) gx(t-3) gru(t-4)

union UHp { uint32_t u; _Float16 s[2]; };
__device__ __forceinline__ uint32_t packh(float a, float b) {
    UHp x; x.s[0] = (_Float16)a; x.s[1] = (_Float16)b; return x.u;
}
__device__ __forceinline__ float dot2(uint32_t w, uint32_t a, float c) {
#if __has_builtin(__builtin_amdgcn_fdot2)
    typedef _Float16 h2 __attribute__((ext_vector_type(2)));
    union U { uint32_t u; h2 h; };
    U W, A; W.u = w; A.u = a;
    return __builtin_amdgcn_fdot2(W.h, A.h, c, false);
#else
    float d;
    asm("v_dot2_f32_f16 %0, %1, %2, %3" : "=v"(d) : "v"(w), "v"(a), "v"(c));
    return d;
#endif
}
__device__ __forceinline__ float fsig(float x)  { return 1.0f / (1.0f + __expf(-x)); }
__device__ __forceinline__ float ftanh(float x) { return 2.0f / (1.0f + __expf(-2.0f * x)) - 1.0f; }

// LDS-only barrier: order LDS writes (lgkmcnt) then raw s_barrier.
// Crucially does NOT drain vmcnt -- __syncthreads() emits
// "s_waitcnt vmcnt(0) lgkmcnt(0)" which put the pixel-prefetch HBM latency
// (~900 cy) on every iteration's critical path (rounds 2/4/7: ~1000 cy/iter
// unexplained stall). Pixel loads now stay in flight across barriers; the
// compiler still inserts the data-dependent vmcnt wait before pxA is used
// one iteration later (~4000 cy of cover).
__device__ __forceinline__ void barrier_lds() {
    asm volatile("s_waitcnt lgkmcnt(0)" ::: "memory");
    __builtin_amdgcn_s_barrier();
}

// all 4 words -> one accumulator
#define D4(ACC, WP, V) \
    do { ACC = dot2((WP)[0], (V).x, ACC); ACC = dot2((WP)[1], (V).y, ACC); \
         ACC = dot2((WP)[2], (V).z, ACC); ACC = dot2((WP)[3], (V).w, ACC); } while (0)
// alternate words across two accumulators (breaks dependent chains)
#define D4X(A, X, WP, V) \
    do { A = dot2((WP)[0], (V).x, A); X = dot2((WP)[1], (V).y, X); \
         A = dot2((WP)[2], (V).z, A); X = dot2((WP)[3], (V).w, X); } while (0)

// Block = 2 batch rows, 448 threads = 7 waves, grid 256 (1 block/CU, one pass).
// (validated round-4 structure; only the in-loop barrier changed)
__global__ __launch_bounds__(448, 2) void rnn_pipe4(
    const float* __restrict__ pix,
    const float* __restrict__ van_wi, const float* __restrict__ van_bi,
    const float* __restrict__ van_wh, const float* __restrict__ van_bh,
    const float* __restrict__ w1g, const float* __restrict__ b1g,
    const float* __restrict__ w2g, const float* __restrict__ b2g,
    const float* __restrict__ gwi, const float* __restrict__ gwh,
    const float* __restrict__ gb,
    const float* __restrict__ mw1, const float* __restrict__ mb1,
    const float* __restrict__ mw2, const float* __restrict__ mb2,
    const float* __restrict__ mw3, const float* __restrict__ mb3,
    const float* __restrict__ sf,
    float* __restrict__ out)
{
    const int tid  = threadIdx.x;
    const int wv   = tid >> 6;
    const int lane = tid & 63;
    const int r0   = 2 * blockIdx.x;

    __shared__ __align__(16) _Float16 xb [2][2][256];   // [buf][row][256]
    __shared__ __align__(16) _Float16 h0b[2][2][32];
    __shared__ __align__(16) _Float16 h1b[2][2][64];
    __shared__ __align__(16) _Float16 h2b[2][2][64];
    __shared__ __align__(16) _Float16 gxb[2][2][192];
    __shared__ __align__(16) _Float16 h3s[2][64];       // [row]
    __shared__ __align__(16) _Float16 rh3s[2][64];
    __shared__ float sHf[2][64];
    __shared__ float sT[2][64];
    __shared__ float sP[2][12];

    uint32_t wreg[128];
    float bz0 = 0.f, bz1 = 0.f, bz2 = 0.f;
    float st0 = 0.f, st1 = 0.f;          // per-role state: lstm c (rows 0/1) or gru h3
    float4 pxA0{}, pxB0{}, pxA1{}, pxB1{};
    const float* pr0 = nullptr; const float* pr1 = nullptr;

    // ---------------- per-role weight load (once) ----------------
    if (wv == 0) {                        // van: x@wi + h0@wh, 2-way k-split (s)
        const int c = lane & 31, s = lane >> 5;
#pragma unroll
        for (int j = 0; j < 64; ++j)
            wreg[j] = packh(van_wi[(128 * s + 2 * j) * 32 + c],
                            van_wi[(128 * s + 2 * j + 1) * 32 + c]);
#pragma unroll
        for (int j = 0; j < 8; ++j)
            wreg[64 + j] = packh(van_wh[(16 * s + 2 * j) * 32 + c],
                                 van_wh[(16 * s + 2 * j + 1) * 32 + c]);
        bz0 = van_bi[c] + van_bh[c];
        pr0 = pix + (size_t)r0 * Tsz * Dsz;
        pr1 = pr0 + (size_t)Tsz * Dsz;
        float4 p0 = *(const float4*)(pr0 + 4 * lane);
        float4 p1 = *(const float4*)(pr1 + 4 * lane);
        uint32_t* x0 = (uint32_t*)xb[1][0];
        uint32_t* x1 = (uint32_t*)xb[1][1];
        x0[2 * lane] = packh(p0.x, p0.y); x0[2 * lane + 1] = packh(p0.z, p0.w);
        x1[2 * lane] = packh(p1.x, p1.y); x1[2 * lane + 1] = packh(p1.z, p1.w);
        pxA0 = *(const float4*)(pr0 + Dsz + 4 * lane);
        pxB0 = *(const float4*)(pr0 + 2 * (size_t)Dsz + 4 * lane);
        pxA1 = *(const float4*)(pr1 + Dsz + 4 * lane);
        pxB1 = *(const float4*)(pr1 + 2 * (size_t)Dsz + 4 * lane);
    } else if (wv <= 2) {                 // lstm1: k=96, cols c0,c1 per lane
        const int p = tid - 64, u = p >> 1, odd = p & 1;
        const int c0 = odd ? 128 + u : u, c1 = c0 + 64;
#pragma unroll
        for (int j = 0; j < 48; ++j)
            wreg[j] = packh(w1g[(2 * j) * 256 + c0], w1g[(2 * j + 1) * 256 + c0]);
#pragma unroll
        for (int j = 0; j < 48; ++j)
            wreg[48 + j] = packh(w1g[(2 * j) * 256 + c1], w1g[(2 * j + 1) * 256 + c1]);
        bz0 = b1g[c0]; bz1 = b1g[c1];
    } else if (wv <= 4) {                 // lstm2: k=128
        const int p = tid - 192, u = p >> 1, odd = p & 1;
        const int c0 = odd ? 128 + u : u, c1 = c0 + 64;
#pragma unroll
        for (int j = 0; j < 64; ++j)
            wreg[j] = packh(w2g[(2 * j) * 256 + c0], w2g[(2 * j + 1) * 256 + c0]);
#pragma unroll
        for (int j = 0; j < 64; ++j)
            wreg[64 + j] = packh(w2g[(2 * j) * 256 + c1], w2g[(2 * j + 1) * 256 + c1]);
        bz0 = b2g[c0]; bz1 = b2g[c1];
    } else if (wv == 5) {                 // gx: h2 @ gru_wi (+ all gru biases)
#pragma unroll
        for (int j = 0; j < 32; ++j) {
            wreg[j]      = packh(gwi[(2 * j) * 192 + lane],       gwi[(2 * j + 1) * 192 + lane]);
            wreg[32 + j] = packh(gwi[(2 * j) * 192 + 64 + lane],  gwi[(2 * j + 1) * 192 + 64 + lane]);
            wreg[64 + j] = packh(gwi[(2 * j) * 192 + 128 + lane], gwi[(2 * j + 1) * 192 + 128 + lane]);
        }
        bz0 = gb[lane]; bz1 = gb[64 + lane]; bz2 = gb[128 + lane];
    } else {                              // gru recurrent: h3 @ gru_wh
#pragma unroll
        for (int j = 0; j < 32; ++j) {
            wreg[j]      = packh(gwh[(2 * j) * 192 + lane],       gwh[(2 * j + 1) * 192 + lane]);
            wreg[32 + j] = packh(gwh[(2 * j) * 192 + 64 + lane],  gwh[(2 * j + 1) * 192 + 64 + lane]);
            wreg[64 + j] = packh(gwh[(2 * j) * 192 + 128 + lane], gwh[(2 * j + 1) * 192 + 128 + lane]);
        }
    }

    for (int i = tid; i < 2 * 2 * 32;  i += 448) ((_Float16*)h0b)[i] = (_Float16)0.f;
    for (int i = tid; i < 2 * 2 * 64;  i += 448) ((_Float16*)h1b)[i] = (_Float16)0.f;
    for (int i = tid; i < 2 * 2 * 64;  i += 448) ((_Float16*)h2b)[i] = (_Float16)0.f;
    for (int i = tid; i < 2 * 2 * 192; i += 448) ((_Float16*)gxb)[i] = (_Float16)0.f;
    for (int i = tid; i < 2 * 64; i += 448) { ((_Float16*)h3s)[i] = (_Float16)0.f; ((_Float16*)rh3s)[i] = (_Float16)0.f; }
    __syncthreads();

    // ---------------- pipelined recurrence ----------------
    for (int n = 0; n < NCYC; ++n) {
        const int wb = n & 1, rb = wb ^ 1;

        if (wv == 0) {
            if (n + 1 < Tsz) {
                uint32_t* x0 = (uint32_t*)xb[wb][0];
                uint32_t* x1 = (uint32_t*)xb[wb][1];
                x0[2 * lane] = packh(pxA0.x, pxA0.y); x0[2 * lane + 1] = packh(pxA0.z, pxA0.w);
                x1[2 * lane] = packh(pxA1.x, pxA1.y); x1[2 * lane + 1] = packh(pxA1.z, pxA1.w);
            }
            pxA0 = pxB0; pxA1 = pxB1;
            if (n + 3 < Tsz) {
                pxB0 = *(const float4*)(pr0 + (size_t)(n + 3) * Dsz + 4 * lane);
                pxB1 = *(const float4*)(pr1 + (size_t)(n + 3) * Dsz + 4 * lane);
            }
            if (n < Tsz) {
                const int c = lane & 31, s = lane >> 5;
#pragma unroll
                for (int r = 0; r < 2; ++r) {
                    const uint4* xq = ((const uint4*)xb[rb][r]) + 16 * s;
                    const uint4* hq = ((const uint4*)h0b[rb][r]) + 2 * s;
                    float a0 = 0.f, a1 = 0.f;
#pragma unroll
                    for (int q = 0; q < 16; q += 2) {
                        uint4 v0 = xq[q], v1 = xq[q + 1];
                        D4(a0, &wreg[4 * q], v0);
                        D4(a1, &wreg[4 * q + 4], v1);
                    }
                    {
                        uint4 v0 = hq[0], v1 = hq[1];
                        D4(a0, &wreg[64], v0);
                        D4(a1, &wreg[68], v1);
                    }
                    float acc = a0 + a1;
                    acc += __shfl_xor(acc, 32);
                    if (s == 0) h0b[wb][r][c] = (_Float16)fmaxf(acc + bz0, 0.f);
                }
            }
        } else if (wv <= 2) {
            const int t = n - 1;
            if (0 <= t && t < Tsz) {
                const int p = tid - 64, u = p >> 1, odd = p & 1;
#pragma unroll
                for (int r = 0; r < 2; ++r) {
                    const uint4* aq = (const uint4*)h0b[rb][r];   // k 0..31
                    const uint4* bq = (const uint4*)h1b[rb][r];   // k 32..95
                    float a0 = bz0, a1 = bz1, x0 = 0.f, x1 = 0.f;
#pragma unroll
                    for (int q = 0; q < 4; ++q) {
                        uint4 v = aq[q];
                        D4X(a0, x0, &wreg[4 * q], v);
                        D4X(a1, x1, &wreg[48 + 4 * q], v);
                    }
#pragma unroll
                    for (int q = 0; q < 8; ++q) {
                        uint4 v = bq[q];
                        D4X(a0, x0, &wreg[16 + 4 * q], v);
                        D4X(a1, x1, &wreg[64 + 4 * q], v);
                    }
                    float g0 = a0 + x0, g1 = a1 + x1;
                    float send = 0.f, fq = 0.f, op = 0.f;
                    if (!odd) send = fsig(g0) * ftanh(g1);        // sig(i)*tanh(g)
                    else { fq = fsig(g0 + 1.f); op = fsig(g1); }  // sig(f+1), sig(o)
                    float prx = __shfl_xor(send, 1);
                    if (odd) {
                        float cs = r ? st1 : st0;
                        cs = fq * cs + prx;
                        if (r) st1 = cs; else st0 = cs;
                        h1b[wb][r][u] = (_Float16)(op * ftanh(cs));
                    }
                }
            }
        } else if (wv <= 4) {
            const int t = n - 2;
            if (0 <= t && t < Tsz) {
                const int p = tid - 192, u = p >> 1, odd = p & 1;
#pragma unroll
                for (int r = 0; r < 2; ++r) {
                    const uint4* aq = (const uint4*)h1b[rb][r];   // k 0..63
                    const uint4* bq = (const uint4*)h2b[rb][r];   // k 64..127
                    float a0 = bz0, a1 = bz1, x0 = 0.f, x1 = 0.f;
#pragma unroll
                    for (int q = 0; q < 8; ++q) {
                        uint4 v = aq[q];
                        D4X(a0, x0, &wreg[4 * q], v);
                        D4X(a1, x1, &wreg[64 + 4 * q], v);
                    }
#pragma unroll
                    for (int q = 0; q < 8; ++q) {
                        uint4 v = bq[q];
                        D4X(a0, x0, &wreg[32 + 4 * q], v);
                        D4X(a1, x1, &wreg[96 + 4 * q], v);
                    }
                    float g0 = a0 + x0, g1 = a1 + x1;
                    float send = 0.f, fq = 0.f, op = 0.f;
                    if (!odd) send = fsig(g0) * ftanh(g1);
                    else { fq = fsig(g0 + 1.f); op = fsig(g1); }
                    float prx = __shfl_xor(send, 1);
                    if (odd) {
                        float cs = r ? st1 : st0;
                        cs = fq * cs + prx;
                        if (r) st1 = cs; else st0 = cs;
                        h2b[wb][r][u] = (_Float16)(op * ftanh(cs));
                    }
                }
            }
        } else if (wv == 5) {
            const int t = n - 3;
            if (0 <= t && t < Tsz) {
#pragma unroll
                for (int r = 0; r < 2; ++r) {
                    const uint4* hq = (const uint4*)h2b[rb][r];
                    float az = bz0, ar = bz1, aa = bz2;
#pragma unroll
                    for (int q = 0; q < 8; ++q) {
                        uint4 v = hq[q];
                        D4(az, &wreg[4 * q], v);
                        D4(ar, &wreg[32 + 4 * q], v);
                        D4(aa, &wreg[64 + 4 * q], v);
                    }
                    gxb[wb][r][lane]       = (_Float16)az;
                    gxb[wb][r][64 + lane]  = (_Float16)ar;
                    gxb[wb][r][128 + lane] = (_Float16)aa;
                }
            }
        } else {
            const int t = n - 4;
            if (0 <= t && t < Tsz) {
                float z0, z1, ga0, ga1;
                {   // row 0 z/r
                    const uint4* hq = (const uint4*)h3s[0];
                    float az = (float)gxb[rb][0][lane], ar = (float)gxb[rb][0][64 + lane];
#pragma unroll
                    for (int q = 0; q < 8; ++q) {
                        uint4 v = hq[q];
                        D4(az, &wreg[4 * q], v);
                        D4(ar, &wreg[32 + 4 * q], v);
                    }
                    z0 = fsig(az);
                    rh3s[0][lane] = (_Float16)(fsig(ar) * st0);
                    ga0 = (float)gxb[rb][0][128 + lane];
                }
                {   // row 1 z/r
                    const uint4* hq = (const uint4*)h3s[1];
                    float az = (float)gxb[rb][1][lane], ar = (float)gxb[rb][1][64 + lane];
#pragma unroll
                    for (int q = 0; q < 8; ++q) {
                        uint4 v = hq[q];
                        D4(az, &wreg[4 * q], v);
                        D4(ar, &wreg[32 + 4 * q], v);
                    }
                    z1 = fsig(az);
                    rh3s[1][lane] = (_Float16)(fsig(ar) * st1);
                    ga1 = (float)gxb[rb][1][128 + lane];
                }
                asm volatile("s_waitcnt lgkmcnt(0)" ::: "memory");   // wave-sync LDS
                {   // row 0 a + update
                    const uint4* rq = (const uint4*)rh3s[0];
                    float aa = ga0, ab = 0.f;
#pragma unroll
                    for (int q = 0; q < 8; ++q) {
                        uint4 v = rq[q];
                        if (q & 1) { D4(ab, &wreg[64 + 4 * q], v); }
                        else       { D4(aa, &wreg[64 + 4 * q], v); }
                    }
                    float av = ftanh(aa + ab);
                    st0 = (1.f - z0) * st0 + z0 * av;
                    h3s[0][lane] = (_Float16)st0;
                }
                {   // row 1 a + update
                    const uint4* rq = (const uint4*)rh3s[1];
                    float aa = ga1, ab = 0.f;
#pragma unroll
                    for (int q = 0; q < 8; ++q) {
                        uint4 v = rq[q];
                        if (q & 1) { D4(ab, &wreg[64 + 4 * q], v); }
                        else       { D4(aa, &wreg[64 + 4 * q], v); }
                    }
                    float av = ftanh(aa + ab);
                    st1 = (1.f - z1) * st1 + z1 * av;
                    h3s[1][lane] = (_Float16)st1;
                }
            }
        }
        barrier_lds();   // LDS-ordered raw barrier: no vmcnt drain (see above)
    }
    __syncthreads();

    // ---------------- MLP head (2 rows) ----------------
    if (wv == 6) { sHf[0][lane] = st0; sHf[1][lane] = st1; }
    __syncthreads();
    if (tid < 64) {
        const int r = tid >> 5, c = tid & 31;
        float acc = mb1[c];
#pragma unroll
        for (int k = 0; k < 64; ++k) acc = fmaf(sHf[r][k], mw1[k * 32 + c], acc);
        sT[r][c] = fmaxf(acc, 0.f);
    }
    __syncthreads();
    if (tid < 64) {
        const int r = tid >> 5, c = tid & 31;
        float acc = mb2[c];
#pragma unroll
        for (int k = 0; k < 32; ++k) acc = fmaf(sT[r][k], mw2[k * 32 + c], acc);
        sT[r][32 + c] = fmaxf(acc, 0.f);
    }
    __syncthreads();
    if (tid < 24) {
        const int r = tid / 12, c = tid - 12 * r;
        float acc = mb3[c];
#pragma unroll
        for (int k = 0; k < 32; ++k) acc = fmaf(sT[r][32 + k], mw3[k * 12 + c], acc);
        sP[r][c] = acc;
    }
    __syncthreads();
    if (tid < 2) {
        float acc = 0.f;
#pragma unroll
        for (int k = 0; k < 12; ++k) acc = fmaf(sP[tid][k], sf[k], acc);
        out[24 + r0 + tid] = acc;
    }
    if (blockIdx.x == 0 && tid < 12) {
        out[tid] = sf[tid];
        out[12 + tid] = 1.0f;
    }
}

extern "C" void kernel_launch(void* const* d_in, const int* in_sizes, int n_in,
                              void* d_out, int out_size, void* d_ws, size_t ws_size,
                              hipStream_t stream) {
    (void)in_sizes; (void)n_in; (void)d_ws; (void)ws_size; (void)out_size;
    const float* pix    = (const float*)d_in[0];
    const float* van_wi = (const float*)d_in[1];
    const float* van_bi = (const float*)d_in[2];
    const float* van_wh = (const float*)d_in[3];
    const float* van_bh = (const float*)d_in[4];
    const float* w1     = (const float*)d_in[5];
    const float* b1     = (const float*)d_in[6];
    const float* w2     = (const float*)d_in[7];
    const float* b2     = (const float*)d_in[8];
    const float* gwi    = (const float*)d_in[9];
    const float* gwh    = (const float*)d_in[10];
    const float* gb     = (const float*)d_in[11];
    const float* mw1    = (const float*)d_in[12];
    const float* mb1    = (const float*)d_in[13];
    const float* mw2    = (const float*)d_in[14];
    const float* mb2    = (const float*)d_in[15];
    const float* mw3    = (const float*)d_in[16];
    const float* mb3    = (const float*)d_in[17];
    const float* sf     = (const float*)d_in[18];
    float* out = (float*)d_out;

    rnn_pipe4<<<256, 448, 0, stream>>>(
        pix, van_wi, van_bi, van_wh, van_bh,
        w1, b1, w2, b2, gwi, gwh, gb,
        mw1, mb1, mw2, mb2, mw3, mb3, sf, out);
}

// Round 9
// 812.641 us; speedup vs baseline: 3.6081x; 1.0489x over previous
//
#include <hip/hip_runtime.h>
#include <stdint.h>

#define Tsz 512
#define Dsz 256
#define NINT 260   // intervals of 2 timesteps; stage offsets: van 0, l1 -2, l2 -4, gx -6, gru -8

union UHp { uint32_t u; _Float16 s[2]; };
__device__ __forceinline__ uint32_t packh(float a, float b) {
    UHp x; x.s[0] = (_Float16)a; x.s[1] = (_Float16)b; return x.u;
}
__device__ __forceinline__ float dot2(uint32_t w, uint32_t a, float c) {
#if __has_builtin(__builtin_amdgcn_fdot2)
    typedef _Float16 h2 __attribute__((ext_vector_type(2)));
    union U { uint32_t u; h2 h; };
    U W, A; W.u = w; A.u = a;
    return __builtin_amdgcn_fdot2(W.h, A.h, c, false);
#else
    float d;
    asm("v_dot2_f32_f16 %0, %1, %2, %3" : "=v"(d) : "v"(w), "v"(a), "v"(c));
    return d;
#endif
}
__device__ __forceinline__ float fsig(float x)  { return 1.0f / (1.0f + __expf(-x)); }
__device__ __forceinline__ float ftanh(float x) { return 2.0f / (1.0f + __expf(-2.0f * x)) - 1.0f; }

// LDS-ordered raw barrier (no vmcnt drain; pixel loads stay in flight)
__device__ __forceinline__ void barrier_lds() {
    asm volatile("s_waitcnt lgkmcnt(0)" ::: "memory");
    __builtin_amdgcn_s_barrier();
}

#define D4(ACC, WP, V) \
    do { ACC = dot2((WP)[0], (V).x, ACC); ACC = dot2((WP)[1], (V).y, ACC); \
         ACC = dot2((WP)[2], (V).z, ACC); ACC = dot2((WP)[3], (V).w, ACC); } while (0)
#define D4X(A, X, WP, V) \
    do { A = dot2((WP)[0], (V).x, A); X = dot2((WP)[1], (V).y, X); \
         A = dot2((WP)[2], (V).z, A); X = dot2((WP)[3], (V).w, X); } while (0)

// Block = 2 batch rows, 512 threads = 8 waves, grid 256 (1 block/CU, one pass).
// Two timesteps per barrier interval; value at timestep t lives in slot t&3.
//  wv0: van (both rows, t=2k,2k+1) + pixel staging (t=2k+2..2k+5 in flight)
//  wv1-2: lstm1 (t=2k-2,2k-1); pair-flag sync before step 2 (partner's h1 half)
//  wv3-4: lstm2 (t=2k-4,2k-3); pair-flag sync likewise
//  wv5: gru gx both rows (t=2k-6,2k-5)
//  wv6/wv7: gru recurrent, one row each (t=2k-8,2k-7)
__global__ __launch_bounds__(512, 1) void rnn_pipe5(
    const float* __restrict__ pix,
    const float* __restrict__ van_wi, const float* __restrict__ van_bi,
    const float* __restrict__ van_wh, const float* __restrict__ van_bh,
    const float* __restrict__ w1g, const float* __restrict__ b1g,
    const float* __restrict__ w2g, const float* __restrict__ b2g,
    const float* __restrict__ gwi, const float* __restrict__ gwh,
    const float* __restrict__ gb,
    const float* __restrict__ mw1, const float* __restrict__ mb1,
    const float* __restrict__ mw2, const float* __restrict__ mb2,
    const float* __restrict__ mw3, const float* __restrict__ mb3,
    const float* __restrict__ sf,
    float* __restrict__ out)
{
    const int tid  = threadIdx.x;
    const int wv   = tid >> 6;
    const int lane = tid & 63;
    const int r0   = 2 * blockIdx.x;

    __shared__ __align__(16) _Float16 xb [4][2][256];   // [slot][row]
    __shared__ __align__(16) _Float16 h0b[4][2][32];
    __shared__ __align__(16) _Float16 h1b[4][2][64];
    __shared__ __align__(16) _Float16 h2b[4][2][64];
    __shared__ __align__(16) _Float16 gxb[4][2][192];
    __shared__ __align__(16) _Float16 h3s[2][64];       // gru-wave private per row
    __shared__ __align__(16) _Float16 rh3s[2][64];
    __shared__ int flg[4];                              // 0,1: lstm1 pair; 2,3: lstm2 pair
    __shared__ float sHf[2][64];
    __shared__ float sT[2][64];
    __shared__ float sP[2][12];

    uint32_t wreg[128];
    float bz0 = 0.f, bz1 = 0.f, bz2 = 0.f;
    float st0 = 0.f, st1 = 0.f;          // lstm c (rows 0/1) or gru h3 (own row)
    float4 pxS[4];                        // [2 timesteps][2 rows], wv0 only
    const float* pr0 = nullptr; const float* pr1 = nullptr;

    // ---------------- per-role weight load (once) ----------------
    if (wv == 0) {                        // van: x@wi + h0@wh, 2-way k-split
        const int c = lane & 31, s = lane >> 5;
#pragma unroll
        for (int j = 0; j < 64; ++j)
            wreg[j] = packh(van_wi[(128 * s + 2 * j) * 32 + c],
                            van_wi[(128 * s + 2 * j + 1) * 32 + c]);
#pragma unroll
        for (int j = 0; j < 8; ++j)
            wreg[64 + j] = packh(van_wh[(16 * s + 2 * j) * 32 + c],
                                 van_wh[(16 * s + 2 * j + 1) * 32 + c]);
        bz0 = van_bi[c] + van_bh[c];
        pr0 = pix + (size_t)r0 * Tsz * Dsz;
        pr1 = pr0 + (size_t)Tsz * Dsz;
        // prologue: x(0),x(1) -> slots 0,1 ; pxS <- x(2),x(3)
#pragma unroll
        for (int t = 0; t < 2; ++t) {
            float4 p0 = *(const float4*)(pr0 + (size_t)t * Dsz + 4 * lane);
            float4 p1 = *(const float4*)(pr1 + (size_t)t * Dsz + 4 * lane);
            uint32_t* x0 = (uint32_t*)xb[t][0];
            uint32_t* x1 = (uint32_t*)xb[t][1];
            x0[2 * lane] = packh(p0.x, p0.y); x0[2 * lane + 1] = packh(p0.z, p0.w);
            x1[2 * lane] = packh(p1.x, p1.y); x1[2 * lane + 1] = packh(p1.z, p1.w);
        }
        pxS[0] = *(const float4*)(pr0 + 2 * (size_t)Dsz + 4 * lane);
        pxS[1] = *(const float4*)(pr1 + 2 * (size_t)Dsz + 4 * lane);
        pxS[2] = *(const float4*)(pr0 + 3 * (size_t)Dsz + 4 * lane);
        pxS[3] = *(const float4*)(pr1 + 3 * (size_t)Dsz + 4 * lane);
    } else if (wv <= 2) {                 // lstm1: k=96, cols c0,c1 per lane
        const int p = tid - 64, u = p >> 1, odd = p & 1;
        const int c0 = odd ? 128 + u : u, c1 = c0 + 64;
#pragma unroll
        for (int j = 0; j < 48; ++j)
            wreg[j] = packh(w1g[(2 * j) * 256 + c0], w1g[(2 * j + 1) * 256 + c0]);
#pragma unroll
        for (int j = 0; j < 48; ++j)
            wreg[48 + j] = packh(w1g[(2 * j) * 256 + c1], w1g[(2 * j + 1) * 256 + c1]);
        bz0 = b1g[c0]; bz1 = b1g[c1];
    } else if (wv <= 4) {                 // lstm2: k=128
        const int p = tid - 192, u = p >> 1, odd = p & 1;
        const int c0 = odd ? 128 + u : u, c1 = c0 + 64;
#pragma unroll
        for (int j = 0; j < 64; ++j)
            wreg[j] = packh(w2g[(2 * j) * 256 + c0], w2g[(2 * j + 1) * 256 + c0]);
#pragma unroll
        for (int j = 0; j < 64; ++j)
            wreg[64 + j] = packh(w2g[(2 * j) * 256 + c1], w2g[(2 * j + 1) * 256 + c1]);
        bz0 = b2g[c0]; bz1 = b2g[c1];
    } else if (wv == 5) {                 // gx: h2 @ gru_wi (+ all gru biases)
#pragma unroll
        for (int j = 0; j < 32; ++j) {
            wreg[j]      = packh(gwi[(2 * j) * 192 + lane],       gwi[(2 * j + 1) * 192 + lane]);
            wreg[32 + j] = packh(gwi[(2 * j) * 192 + 64 + lane],  gwi[(2 * j + 1) * 192 + 64 + lane]);
            wreg[64 + j] = packh(gwi[(2 * j) * 192 + 128 + lane], gwi[(2 * j + 1) * 192 + 128 + lane]);
        }
        bz0 = gb[lane]; bz1 = gb[64 + lane]; bz2 = gb[128 + lane];
    } else {                              // wv6/wv7: gru recurrent, gwh z|r|a (same weights)
#pragma unroll
        for (int j = 0; j < 32; ++j) {
            wreg[j]      = packh(gwh[(2 * j) * 192 + lane],       gwh[(2 * j + 1) * 192 + lane]);
            wreg[32 + j] = packh(gwh[(2 * j) * 192 + 64 + lane],  gwh[(2 * j + 1) * 192 + 64 + lane]);
            wreg[64 + j] = packh(gwh[(2 * j) * 192 + 128 + lane], gwh[(2 * j + 1) * 192 + 128 + lane]);
        }
    }

    for (int i = tid; i < 4 * 2 * 32;  i += 512) ((_Float16*)h0b)[i] = (_Float16)0.f;
    for (int i = tid; i < 4 * 2 * 64;  i += 512) ((_Float16*)h1b)[i] = (_Float16)0.f;
    for (int i = tid; i < 4 * 2 * 64;  i += 512) ((_Float16*)h2b)[i] = (_Float16)0.f;
    for (int i = tid; i < 4 * 2 * 192; i += 512) ((_Float16*)gxb)[i] = (_Float16)0.f;
    for (int i = tid; i < 2 * 64; i += 512) { ((_Float16*)h3s)[i] = (_Float16)0.f; ((_Float16*)rh3s)[i] = (_Float16)0.f; }
    if (tid < 4) flg[tid] = 0;
    __syncthreads();

    // ---------------- pipelined recurrence, 2 timesteps / interval ----------------
    for (int k = 0; k < NINT; ++k) {

        if (wv == 0) {
            // stage x(2k+2),x(2k+3) from regs; then refill regs with x(2k+4),x(2k+5)
#pragma unroll
            for (int s = 0; s < 2; ++s) {
                const int t2 = 2 * k + 2 + s;
                if (t2 < Tsz) {
                    uint32_t* x0 = (uint32_t*)xb[t2 & 3][0];
                    uint32_t* x1 = (uint32_t*)xb[t2 & 3][1];
                    float4 a0 = pxS[2 * s], a1 = pxS[2 * s + 1];
                    x0[2 * lane] = packh(a0.x, a0.y); x0[2 * lane + 1] = packh(a0.z, a0.w);
                    x1[2 * lane] = packh(a1.x, a1.y); x1[2 * lane + 1] = packh(a1.z, a1.w);
                }
            }
#pragma unroll
            for (int s = 0; s < 2; ++s) {
                const int t4 = 2 * k + 4 + s;
                if (t4 < Tsz) {
                    pxS[2 * s]     = *(const float4*)(pr0 + (size_t)t4 * Dsz + 4 * lane);
                    pxS[2 * s + 1] = *(const float4*)(pr1 + (size_t)t4 * Dsz + 4 * lane);
                }
            }
            const int c = lane & 31, ssp = lane >> 5;
#pragma unroll
            for (int s = 0; s < 2; ++s) {
                const int t = 2 * k + s;
                if (t < Tsz) {
#pragma unroll
                    for (int r = 0; r < 2; ++r) {
                        const uint4* xq = ((const uint4*)xb[t & 3][r]) + 16 * ssp;
                        const uint4* hq = ((const uint4*)h0b[(t - 1) & 3][r]) + 2 * ssp;
                        float a0 = 0.f, a1 = 0.f;
#pragma unroll
                        for (int q = 0; q < 16; q += 2) {
                            uint4 v0 = xq[q], v1 = xq[q + 1];
                            D4(a0, &wreg[4 * q], v0);
                            D4(a1, &wreg[4 * q + 4], v1);
                        }
                        {
                            uint4 v0 = hq[0], v1 = hq[1];
                            D4(a0, &wreg[64], v0);
                            D4(a1, &wreg[68], v1);
                        }
                        float acc = a0 + a1;
                        acc += __shfl_xor(acc, 32);
                        if (ssp == 0) h0b[t & 3][r][c] = (_Float16)fmaxf(acc + bz0, 0.f);
                    }
                }
            }
        } else if (wv <= 2) {
            const int p = tid - 64, u = p >> 1, odd = p & 1;
#pragma unroll
            for (int s = 0; s < 2; ++s) {
                const int t = 2 * k - 2 + s;
                if (s == 1) {
                    // pair sync: partner's h1(t-1) half was written in step 0
                    asm volatile("s_waitcnt lgkmcnt(0)" ::: "memory");
                    if (lane == 0) *((volatile int*)&flg[wv - 1]) = k + 1;
                    volatile int* pf = (volatile int*)&flg[(wv - 1) ^ 1];
                    while (*pf < k + 1) {}
                    asm volatile("" ::: "memory");
                }
                if (0 <= t && t < Tsz) {
#pragma unroll
                    for (int r = 0; r < 2; ++r) {
                        const uint4* aq = (const uint4*)h0b[t & 3][r];        // k 0..31
                        const uint4* bq = (const uint4*)h1b[(t - 1) & 3][r];  // k 32..95
                        float a0 = bz0, a1 = bz1, x0 = 0.f, x1 = 0.f;
#pragma unroll
                        for (int q = 0; q < 4; ++q) {
                            uint4 v = aq[q];
                            D4X(a0, x0, &wreg[4 * q], v);
                            D4X(a1, x1, &wreg[48 + 4 * q], v);
                        }
#pragma unroll
                        for (int q = 0; q < 8; ++q) {
                            uint4 v = bq[q];
                            D4X(a0, x0, &wreg[16 + 4 * q], v);
                            D4X(a1, x1, &wreg[64 + 4 * q], v);
                        }
                        float g0 = a0 + x0, g1 = a1 + x1;
                        float send = 0.f, fq = 0.f, op = 0.f;
                        if (!odd) send = fsig(g0) * ftanh(g1);
                        else { fq = fsig(g0 + 1.f); op = fsig(g1); }
                        float prx = __shfl_xor(send, 1);
                        if (odd) {
                            float cs = r ? st1 : st0;
                            cs = fq * cs + prx;
                            if (r) st1 = cs; else st0 = cs;
                            h1b[t & 3][r][u] = (_Float16)(op * ftanh(cs));
                        }
                    }
                }
            }
        } else if (wv <= 4) {
            const int p = tid - 192, u = p >> 1, odd = p & 1;
#pragma unroll
            for (int s = 0; s < 2; ++s) {
                const int t = 2 * k - 4 + s;
                if (s == 1) {
                    asm volatile("s_waitcnt lgkmcnt(0)" ::: "memory");
                    if (lane == 0) *((volatile int*)&flg[wv - 1]) = k + 1;
                    volatile int* pf = (volatile int*)&flg[(wv - 1) ^ 1];
                    while (*pf < k + 1) {}
                    asm volatile("" ::: "memory");
                }
                if (0 <= t && t < Tsz) {
#pragma unroll
                    for (int r = 0; r < 2; ++r) {
                        const uint4* aq = (const uint4*)h1b[t & 3][r];        // k 0..63
                        const uint4* bq = (const uint4*)h2b[(t - 1) & 3][r];  // k 64..127
                        float a0 = bz0, a1 = bz1, x0 = 0.f, x1 = 0.f;
#pragma unroll
                        for (int q = 0; q < 8; ++q) {
                            uint4 v = aq[q];
                            D4X(a0, x0, &wreg[4 * q], v);
                            D4X(a1, x1, &wreg[64 + 4 * q], v);
                        }
#pragma unroll
                        for (int q = 0; q < 8; ++q) {
                            uint4 v = bq[q];
                            D4X(a0, x0, &wreg[32 + 4 * q], v);
                            D4X(a1, x1, &wreg[96 + 4 * q], v);
                        }
                        float g0 = a0 + x0, g1 = a1 + x1;
                        float send = 0.f, fq = 0.f, op = 0.f;
                        if (!odd) send = fsig(g0) * ftanh(g1);
                        else { fq = fsig(g0 + 1.f); op = fsig(g1); }
                        float prx = __shfl_xor(send, 1);
                        if (odd) {
                            float cs = r ? st1 : st0;
                            cs = fq * cs + prx;
                            if (r) st1 = cs; else st0 = cs;
                            h2b[t & 3][r][u] = (_Float16)(op * ftanh(cs));
                        }
                    }
                }
            }
        } else if (wv == 5) {
#pragma unroll
            for (int s = 0; s < 2; ++s) {
                const int t = 2 * k - 6 + s;
                if (0 <= t && t < Tsz) {
#pragma unroll
                    for (int r = 0; r < 2; ++r) {
                        const uint4* hq = (const uint4*)h2b[t & 3][r];
                        float az = bz0, ar = bz1, aa = bz2;
#pragma unroll
                        for (int q = 0; q < 8; ++q) {
                            uint4 v = hq[q];
                            D4(az, &wreg[4 * q], v);
                            D4(ar, &wreg[32 + 4 * q], v);
                            D4(aa, &wreg[64 + 4 * q], v);
                        }
                        gxb[t & 3][r][lane]       = (_Float16)az;
                        gxb[t & 3][r][64 + lane]  = (_Float16)ar;
                        gxb[t & 3][r][128 + lane] = (_Float16)aa;
                    }
                }
            }
        } else {
            const int r = wv - 6;
#pragma unroll
            for (int s = 0; s < 2; ++s) {
                const int t = 2 * k - 8 + s;
                if (0 <= t && t < Tsz) {
                    const uint4* hq = (const uint4*)h3s[r];
                    float az = (float)gxb[t & 3][r][lane];
                    float ar = (float)gxb[t & 3][r][64 + lane];
#pragma unroll
                    for (int q = 0; q < 8; ++q) {
                        uint4 v = hq[q];
                        D4(az, &wreg[4 * q], v);
                        D4(ar, &wreg[32 + 4 * q], v);
                    }
                    float z = fsig(az);
                    rh3s[r][lane] = (_Float16)(fsig(ar) * st0);
                    float ga = (float)gxb[t & 3][r][128 + lane];
                    asm volatile("s_waitcnt lgkmcnt(0)" ::: "memory");   // wave-sync LDS
                    const uint4* rq = (const uint4*)rh3s[r];
                    float aa = ga, ab = 0.f;
#pragma unroll
                    for (int q = 0; q < 8; ++q) {
                        uint4 v = rq[q];
                        if (q & 1) { D4(ab, &wreg[64 + 4 * q], v); }
                        else       { D4(aa, &wreg[64 + 4 * q], v); }
                    }
                    float av = ftanh(aa + ab);
                    st0 = (1.f - z) * st0 + z * av;
                    h3s[r][lane] = (_Float16)st0;
                }
            }
        }
        barrier_lds();
    }
    __syncthreads();

    // ---------------- MLP head (2 rows) ----------------
    if (wv == 6) sHf[0][lane] = st0;
    if (wv == 7) sHf[1][lane] = st0;
    __syncthreads();
    if (tid < 64) {
        const int r = tid >> 5, c = tid & 31;
        float acc = mb1[c];
#pragma unroll
        for (int kk = 0; kk < 64; ++kk) acc = fmaf(sHf[r][kk], mw1[kk * 32 + c], acc);
        sT[r][c] = fmaxf(acc, 0.f);
    }
    __syncthreads();
    if (tid < 64) {
        const int r = tid >> 5, c = tid & 31;
        float acc = mb2[c];
#pragma unroll
        for (int kk = 0; kk < 32; ++kk) acc = fmaf(sT[r][kk], mw2[kk * 32 + c], acc);
        sT[r][32 + c] = fmaxf(acc, 0.f);
    }
    __syncthreads();
    if (tid < 24) {
        const int r = tid / 12, c = tid - 12 * r;
        float acc = mb3[c];
#pragma unroll
        for (int kk = 0; kk < 32; ++kk) acc = fmaf(sT[r][32 + kk], mw3[kk * 12 + c], acc);
        sP[r][c] = acc;
    }
    __syncthreads();
    if (tid < 2) {
        float acc = 0.f;
#pragma unroll
        for (int kk = 0; kk < 12; ++kk) acc = fmaf(sP[tid][kk], sf[kk], acc);
        out[24 + r0 + tid] = acc;
    }
    if (blockIdx.x == 0 && tid < 12) {
        out[tid] = sf[tid];
        out[12 + tid] = 1.0f;
    }
}

extern "C" void kernel_launch(void* const* d_in, const int* in_sizes, int n_in,
                              void* d_out, int out_size, void* d_ws, size_t ws_size,
                              hipStream_t stream) {
    (void)in_sizes; (void)n_in; (void)d_ws; (void)ws_size; (void)out_size;
    const float* pix    = (const float*)d_in[0];
    const float* van_wi = (const float*)d_in[1];
    const float* van_bi = (const float*)d_in[2];
    const float* van_wh = (const float*)d_in[3];
    const float* van_bh = (const float*)d_in[4];
    const float* w1     = (const float*)d_in[5];
    const float* b1     = (const float*)d_in[6];
    const float* w2     = (const float*)d_in[7];
    const float* b2     = (const float*)d_in[8];
    const float* gwi    = (const float*)d_in[9];
    const float* gwh    = (const float*)d_in[10];
    const float* gb     = (const float*)d_in[11];
    const float* mw1    = (const float*)d_in[12];
    const float* mb1    = (const float*)d_in[13];
    const float* mw2    = (const float*)d_in[14];
    const float* mb2    = (const float*)d_in[15];
    const float* mw3    = (const float*)d_in[16];
    const float* mb3    = (const float*)d_in[17];
    const float* sf     = (const float*)d_in[18];
    float* out = (float*)d_out;

    rnn_pipe5<<<256, 512, 0, stream>>>(
        pix, van_wi, van_bi, van_wh, van_bh,
        w1, b1, w2, b2, gwi, gwh, gb,
        mw1, mb1, mw2, mb2, mw3, mb3, sf, out);
}

// Round 10
// 781.064 us; speedup vs baseline: 3.7540x; 1.0404x over previous
//
#include <hip/hip_runtime.h>
#include <stdint.h>

#define Tsz 512
#define Dsz 256

// role ids (prog[] index)
#define R_VAN 0
#define R_L1A 1
#define R_L1B 2
#define R_L2A 3
#define R_L2B 4
#define R_GX  5
#define R_GR0 6
#define R_GR1 7

union UHp { uint32_t u; _Float16 s[2]; };
__device__ __forceinline__ uint32_t packh(float a, float b) {
    UHp x; x.s[0] = (_Float16)a; x.s[1] = (_Float16)b; return x.u;
}
__device__ __forceinline__ float dot2(uint32_t w, uint32_t a, float c) {
#if __has_builtin(__builtin_amdgcn_fdot2)
    typedef _Float16 h2 __attribute__((ext_vector_type(2)));
    union U { uint32_t u; h2 h; };
    U W, A; W.u = w; A.u = a;
    return __builtin_amdgcn_fdot2(W.h, A.h, c, false);
#else
    float d;
    asm("v_dot2_f32_f16 %0, %1, %2, %3" : "=v"(d) : "v"(w), "v"(a), "v"(c));
    return d;
#endif
}
__device__ __forceinline__ float fsig(float x)  { return 1.0f / (1.0f + __expf(-x)); }
__device__ __forceinline__ float ftanh(float x) { return 2.0f / (1.0f + __expf(-2.0f * x)) - 1.0f; }

#define D4(ACC, WP, V) \
    do { ACC = dot2((WP)[0], (V).x, ACC); ACC = dot2((WP)[1], (V).y, ACC); \
         ACC = dot2((WP)[2], (V).z, ACC); ACC = dot2((WP)[3], (V).w, ACC); } while (0)
#define D4X(A, X, WP, V) \
    do { A = dot2((WP)[0], (V).x, A); X = dot2((WP)[1], (V).y, X); \
         A = dot2((WP)[2], (V).z, A); X = dot2((WP)[3], (V).w, X); } while (0)

// Cached flag wait: re-read LDS counter only when cached value insufficient.
// Monotonic counters -> one read typically covers several timesteps.
#define WAITGE(cache, ridx, need) \
    do { if ((cache) < (need)) { \
        volatile const int* _pf = (volatile const int*)&prog[(ridx)]; \
        int _v = *_pf; \
        while (_v < (need)) _v = *_pf; \
        (cache) = _v; } } while (0)

// Data writes (DS, in order per wave) drained, then publish progress.
#define SIGNAL(ridx, val) \
    do { asm volatile("s_waitcnt lgkmcnt(0)" ::: "memory"); \
         *((volatile int*)&prog[(ridx)]) = (val); } while (0)

// Block = 2 batch rows, 512 threads = 8 waves, grid 256 (1 block/CU, one pass).
// NO in-loop barriers: each wave runs its own t-loop, synced by prog[] flags
// on true dataflow edges only (elastic pipeline). 4-slot rotating buffers
// (slot = t&3) give 4-deep slack; backpressure edges keep reuse safe.
// Role->wave map pairs heavy+light per SIMD (SIMD = wv&3):
//   SIMD0: wv0=L2A + wv4=GRU0   SIMD1: wv1=L2B + wv5=GRU1
//   SIMD2: wv2=VAN + wv6=L1A    SIMD3: wv3=GX  + wv7=L1B
__global__ __launch_bounds__(512, 1) void rnn_flag(
    const float* __restrict__ pix,
    const float* __restrict__ van_wi, const float* __restrict__ van_bi,
    const float* __restrict__ van_wh, const float* __restrict__ van_bh,
    const float* __restrict__ w1g, const float* __restrict__ b1g,
    const float* __restrict__ w2g, const float* __restrict__ b2g,
    const float* __restrict__ gwi, const float* __restrict__ gwh,
    const float* __restrict__ gb,
    const float* __restrict__ mw1, const float* __restrict__ mb1,
    const float* __restrict__ mw2, const float* __restrict__ mb2,
    const float* __restrict__ mw3, const float* __restrict__ mb3,
    const float* __restrict__ sf,
    float* __restrict__ out)
{
    const int tid  = threadIdx.x;
    const int wv   = tid >> 6;
    const int lane = tid & 63;
    const int r0   = 2 * blockIdx.x;

    int role;
    switch (wv) {
        case 0: role = R_L2A; break;
        case 1: role = R_L2B; break;
        case 2: role = R_VAN; break;
        case 3: role = R_GX;  break;
        case 4: role = R_GR0; break;
        case 5: role = R_GR1; break;
        case 6: role = R_L1A; break;
        default: role = R_L1B; break;
    }

    __shared__ __align__(16) _Float16 xb [4][2][256];   // [slot][row]
    __shared__ __align__(16) _Float16 h0b[4][2][32];
    __shared__ __align__(16) _Float16 h1b[4][2][64];
    __shared__ __align__(16) _Float16 h2b[4][2][64];
    __shared__ __align__(16) _Float16 gxb[4][2][192];
    __shared__ __align__(16) _Float16 h3s[2][64];       // gru-wave private per row
    __shared__ __align__(16) _Float16 rh3s[2][64];
    __shared__ int prog[8];
    __shared__ float sHf[2][64];
    __shared__ float sT[2][64];
    __shared__ float sP[2][12];

    uint32_t wreg[128];
    float bz0 = 0.f, bz1 = 0.f, bz2 = 0.f;
    float st0 = 0.f, st1 = 0.f;          // lstm c (rows 0/1) or gru h3 (own row)
    float4 pxA0{}, pxB0{}, pxA1{}, pxB1{};
    const float* pr0 = nullptr; const float* pr1 = nullptr;

    // ---------------- per-role weight load (once) ----------------
    if (role == R_VAN) {
        const int c = lane & 31, s = lane >> 5;
#pragma unroll
        for (int j = 0; j < 64; ++j)
            wreg[j] = packh(van_wi[(128 * s + 2 * j) * 32 + c],
                            van_wi[(128 * s + 2 * j + 1) * 32 + c]);
#pragma unroll
        for (int j = 0; j < 8; ++j)
            wreg[64 + j] = packh(van_wh[(16 * s + 2 * j) * 32 + c],
                                 van_wh[(16 * s + 2 * j + 1) * 32 + c]);
        bz0 = van_bi[c] + van_bh[c];
        pr0 = pix + (size_t)r0 * Tsz * Dsz;
        pr1 = pr0 + (size_t)Tsz * Dsz;
        // prologue: x(0),x(1) -> slots 0,1; pxA=x(2), pxB=x(3)
#pragma unroll
        for (int t = 0; t < 2; ++t) {
            float4 p0 = *(const float4*)(pr0 + (size_t)t * Dsz + 4 * lane);
            float4 p1 = *(const float4*)(pr1 + (size_t)t * Dsz + 4 * lane);
            uint32_t* x0 = (uint32_t*)xb[t][0];
            uint32_t* x1 = (uint32_t*)xb[t][1];
            x0[2 * lane] = packh(p0.x, p0.y); x0[2 * lane + 1] = packh(p0.z, p0.w);
            x1[2 * lane] = packh(p1.x, p1.y); x1[2 * lane + 1] = packh(p1.z, p1.w);
        }
        pxA0 = *(const float4*)(pr0 + 2 * (size_t)Dsz + 4 * lane);
        pxA1 = *(const float4*)(pr1 + 2 * (size_t)Dsz + 4 * lane);
        pxB0 = *(const float4*)(pr0 + 3 * (size_t)Dsz + 4 * lane);
        pxB1 = *(const float4*)(pr1 + 3 * (size_t)Dsz + 4 * lane);
    } else if (role == R_L1A || role == R_L1B) {
        const int p = (role == R_L1A ? 0 : 64) + lane;
        const int u = p >> 1, odd = p & 1;
        const int c0 = odd ? 128 + u : u, c1 = c0 + 64;
#pragma unroll
        for (int j = 0; j < 48; ++j)
            wreg[j] = packh(w1g[(2 * j) * 256 + c0], w1g[(2 * j + 1) * 256 + c0]);
#pragma unroll
        for (int j = 0; j < 48; ++j)
            wreg[48 + j] = packh(w1g[(2 * j) * 256 + c1], w1g[(2 * j + 1) * 256 + c1]);
        bz0 = b1g[c0]; bz1 = b1g[c1];
    } else if (role == R_L2A || role == R_L2B) {
        const int p = (role == R_L2A ? 0 : 64) + lane;
        const int u = p >> 1, odd = p & 1;
        const int c0 = odd ? 128 + u : u, c1 = c0 + 64;
#pragma unroll
        for (int j = 0; j < 64; ++j)
            wreg[j] = packh(w2g[(2 * j) * 256 + c0], w2g[(2 * j + 1) * 256 + c0]);
#pragma unroll
        for (int j = 0; j < 64; ++j)
            wreg[64 + j] = packh(w2g[(2 * j) * 256 + c1], w2g[(2 * j + 1) * 256 + c1]);
        bz0 = b2g[c0]; bz1 = b2g[c1];
    } else if (role == R_GX) {
#pragma unroll
        for (int j = 0; j < 32; ++j) {
            wreg[j]      = packh(gwi[(2 * j) * 192 + lane],       gwi[(2 * j + 1) * 192 + lane]);
            wreg[32 + j] = packh(gwi[(2 * j) * 192 + 64 + lane],  gwi[(2 * j + 1) * 192 + 64 + lane]);
            wreg[64 + j] = packh(gwi[(2 * j) * 192 + 128 + lane], gwi[(2 * j + 1) * 192 + 128 + lane]);
        }
        bz0 = gb[lane]; bz1 = gb[64 + lane]; bz2 = gb[128 + lane];
    } else {   // R_GR0 / R_GR1
#pragma unroll
        for (int j = 0; j < 32; ++j) {
            wreg[j]      = packh(gwh[(2 * j) * 192 + lane],       gwh[(2 * j + 1) * 192 + lane]);
            wreg[32 + j] = packh(gwh[(2 * j) * 192 + 64 + lane],  gwh[(2 * j + 1) * 192 + 64 + lane]);
            wreg[64 + j] = packh(gwh[(2 * j) * 192 + 128 + lane], gwh[(2 * j + 1) * 192 + 128 + lane]);
        }
    }

    for (int i = tid; i < 4 * 2 * 32;  i += 512) ((_Float16*)h0b)[i] = (_Float16)0.f;
    for (int i = tid; i < 4 * 2 * 64;  i += 512) ((_Float16*)h1b)[i] = (_Float16)0.f;
    for (int i = tid; i < 4 * 2 * 64;  i += 512) ((_Float16*)h2b)[i] = (_Float16)0.f;
    for (int i = tid; i < 4 * 2 * 192; i += 512) ((_Float16*)gxb)[i] = (_Float16)0.f;
    for (int i = tid; i < 2 * 64; i += 512) { ((_Float16*)h3s)[i] = (_Float16)0.f; ((_Float16*)rh3s)[i] = (_Float16)0.f; }
    if (tid < 8) prog[tid] = 0;
    __syncthreads();

    // ---------------- elastic pipelined recurrence (no barriers) ----------------
    if (role == R_VAN) {
        const int c = lane & 31, s = lane >> 5;
        int cA = 0, cB = 0;
        for (int t = 0; t < Tsz; ++t) {
            // before overwriting h0(t-4): both l1 waves must have consumed it
            WAITGE(cA, R_L1A, t - 3);
            WAITGE(cB, R_L1B, t - 3);
            // stage x(t+2) (held in pxA), advance prefetch to x(t+4)
            if (t + 2 < Tsz) {
                uint32_t* x0 = (uint32_t*)xb[(t + 2) & 3][0];
                uint32_t* x1 = (uint32_t*)xb[(t + 2) & 3][1];
                x0[2 * lane] = packh(pxA0.x, pxA0.y); x0[2 * lane + 1] = packh(pxA0.z, pxA0.w);
                x1[2 * lane] = packh(pxA1.x, pxA1.y); x1[2 * lane + 1] = packh(pxA1.z, pxA1.w);
            }
            pxA0 = pxB0; pxA1 = pxB1;
            if (t + 4 < Tsz) {
                pxB0 = *(const float4*)(pr0 + (size_t)(t + 4) * Dsz + 4 * lane);
                pxB1 = *(const float4*)(pr1 + (size_t)(t + 4) * Dsz + 4 * lane);
            }
#pragma unroll
            for (int r = 0; r < 2; ++r) {
                const uint4* xq = ((const uint4*)xb[t & 3][r]) + 16 * s;
                const uint4* hq = ((const uint4*)h0b[(t - 1) & 3][r]) + 2 * s;
                float a0 = 0.f, a1 = 0.f;
#pragma unroll
                for (int q = 0; q < 16; q += 2) {
                    uint4 v0 = xq[q], v1 = xq[q + 1];
                    D4(a0, &wreg[4 * q], v0);
                    D4(a1, &wreg[4 * q + 4], v1);
                }
                {
                    uint4 v0 = hq[0], v1 = hq[1];
                    D4(a0, &wreg[64], v0);
                    D4(a1, &wreg[68], v1);
                }
                float acc = a0 + a1;
                acc += __shfl_xor(acc, 32);
                if (s == 0) h0b[t & 3][r][c] = (_Float16)fmaxf(acc + bz0, 0.f);
            }
            SIGNAL(R_VAN, t + 1);
        }
    } else if (role == R_L1A || role == R_L1B) {
        const int prt = (role == R_L1A) ? R_L1B : R_L1A;
        const int p = (role == R_L1A ? 0 : 64) + lane;
        const int u = p >> 1, odd = p & 1;
        int cv = 0, cp = 0, c2a = 0, c2b = 0;
        for (int t = 0; t < Tsz; ++t) {
            WAITGE(cv, R_VAN, t + 1);          // h0(t) ready
            WAITGE(cp, prt, t);                // partner's h1(t-1) half ready
            WAITGE(c2a, R_L2A, t - 3);         // h1(t-4) consumed before overwrite
            WAITGE(c2b, R_L2B, t - 3);
#pragma unroll
            for (int r = 0; r < 2; ++r) {
                const uint4* aq = (const uint4*)h0b[t & 3][r];        // k 0..31
                const uint4* bq = (const uint4*)h1b[(t - 1) & 3][r];  // k 32..95
                float a0 = bz0, a1 = bz1, x0 = 0.f, x1 = 0.f;
#pragma unroll
                for (int q = 0; q < 4; ++q) {
                    uint4 v = aq[q];
                    D4X(a0, x0, &wreg[4 * q], v);
                    D4X(a1, x1, &wreg[48 + 4 * q], v);
                }
#pragma unroll
                for (int q = 0; q < 8; ++q) {
                    uint4 v = bq[q];
                    D4X(a0, x0, &wreg[16 + 4 * q], v);
                    D4X(a1, x1, &wreg[64 + 4 * q], v);
                }
                float g0 = a0 + x0, g1 = a1 + x1;
                float send = 0.f, fq = 0.f, op = 0.f;
                if (!odd) send = fsig(g0) * ftanh(g1);
                else { fq = fsig(g0 + 1.f); op = fsig(g1); }
                float prx = __shfl_xor(send, 1);
                if (odd) {
                    float cs = r ? st1 : st0;
                    cs = fq * cs + prx;
                    if (r) st1 = cs; else st0 = cs;
                    h1b[t & 3][r][u] = (_Float16)(op * ftanh(cs));
                }
            }
            SIGNAL(role, t + 1);
        }
    } else if (role == R_L2A || role == R_L2B) {
        const int prt = (role == R_L2A) ? R_L2B : R_L2A;
        const int p = (role == R_L2A ? 0 : 64) + lane;
        const int u = p >> 1, odd = p & 1;
        int c1a = 0, c1b = 0, cp = 0, cg = 0;
        for (int t = 0; t < Tsz; ++t) {
            WAITGE(c1a, R_L1A, t + 1);         // h1(t) ready (both halves)
            WAITGE(c1b, R_L1B, t + 1);
            WAITGE(cp, prt, t);                // partner's h2(t-1) half
            WAITGE(cg, R_GX, t - 3);           // h2(t-4) consumed before overwrite
#pragma unroll
            for (int r = 0; r < 2; ++r) {
                const uint4* aq = (const uint4*)h1b[t & 3][r];        // k 0..63
                const uint4* bq = (const uint4*)h2b[(t - 1) & 3][r];  // k 64..127
                float a0 = bz0, a1 = bz1, x0 = 0.f, x1 = 0.f;
#pragma unroll
                for (int q = 0; q < 8; ++q) {
                    uint4 v = aq[q];
                    D4X(a0, x0, &wreg[4 * q], v);
                    D4X(a1, x1, &wreg[64 + 4 * q], v);
                }
#pragma unroll
                for (int q = 0; q < 8; ++q) {
                    uint4 v = bq[q];
                    D4X(a0, x0, &wreg[32 + 4 * q], v);
                    D4X(a1, x1, &wreg[96 + 4 * q], v);
                }
                float g0 = a0 + x0, g1 = a1 + x1;
                float send = 0.f, fq = 0.f, op = 0.f;
                if (!odd) send = fsig(g0) * ftanh(g1);
                else { fq = fsig(g0 + 1.f); op = fsig(g1); }
                float prx = __shfl_xor(send, 1);
                if (odd) {
                    float cs = r ? st1 : st0;
                    cs = fq * cs + prx;
                    if (r) st1 = cs; else st0 = cs;
                    h2b[t & 3][r][u] = (_Float16)(op * ftanh(cs));
                }
            }
            SIGNAL(role, t + 1);
        }
    } else if (role == R_GX) {
        int c2a = 0, c2b = 0, g0c = 0, g1c = 0;
        for (int t = 0; t < Tsz; ++t) {
            WAITGE(c2a, R_L2A, t + 1);         // h2(t) ready
            WAITGE(c2b, R_L2B, t + 1);
            WAITGE(g0c, R_GR0, t - 3);         // gxb(t-4) consumed before overwrite
            WAITGE(g1c, R_GR1, t - 3);
#pragma unroll
            for (int r = 0; r < 2; ++r) {
                const uint4* hq = (const uint4*)h2b[t & 3][r];
                float az = bz0, ar = bz1, aa = bz2;
#pragma unroll
                for (int q = 0; q < 8; ++q) {
                    uint4 v = hq[q];
                    D4(az, &wreg[4 * q], v);
                    D4(ar, &wreg[32 + 4 * q], v);
                    D4(aa, &wreg[64 + 4 * q], v);
                }
                gxb[t & 3][r][lane]       = (_Float16)az;
                gxb[t & 3][r][64 + lane]  = (_Float16)ar;
                gxb[t & 3][r][128 + lane] = (_Float16)aa;
            }
            SIGNAL(R_GX, t + 1);
        }
    } else {   // R_GR0 / R_GR1
        const int r = (role == R_GR0) ? 0 : 1;
        int cg = 0;
        for (int t = 0; t < Tsz; ++t) {
            WAITGE(cg, R_GX, t + 1);           // gx(t) ready
            const uint4* hq = (const uint4*)h3s[r];
            float az = (float)gxb[t & 3][r][lane];
            float ar = (float)gxb[t & 3][r][64 + lane];
#pragma unroll
            for (int q = 0; q < 8; ++q) {
                uint4 v = hq[q];
                D4(az, &wreg[4 * q], v);
                D4(ar, &wreg[32 + 4 * q], v);
            }
            float z = fsig(az);
            rh3s[r][lane] = (_Float16)(fsig(ar) * st0);
            float ga = (float)gxb[t & 3][r][128 + lane];
            asm volatile("s_waitcnt lgkmcnt(0)" ::: "memory");   // wave-sync LDS
            const uint4* rq = (const uint4*)rh3s[r];
            float aa = ga, ab = 0.f;
#pragma unroll
            for (int q = 0; q < 8; ++q) {
                uint4 v = rq[q];
                if (q & 1) { D4(ab, &wreg[64 + 4 * q], v); }
                else       { D4(aa, &wreg[64 + 4 * q], v); }
            }
            float av = ftanh(aa + ab);
            st0 = (1.f - z) * st0 + z * av;
            h3s[r][lane] = (_Float16)st0;
            SIGNAL(role, t + 1);
        }
    }

    if (role == R_GR0) sHf[0][lane] = st0;
    if (role == R_GR1) sHf[1][lane] = st0;
    __syncthreads();

    // ---------------- MLP head (2 rows) ----------------
    if (tid < 64) {
        const int r = tid >> 5, c = tid & 31;
        float acc = mb1[c];
#pragma unroll
        for (int kk = 0; kk < 64; ++kk) acc = fmaf(sHf[r][kk], mw1[kk * 32 + c], acc);
        sT[r][c] = fmaxf(acc, 0.f);
    }
    __syncthreads();
    if (tid < 64) {
        const int r = tid >> 5, c = tid & 31;
        float acc = mb2[c];
#pragma unroll
        for (int kk = 0; kk < 32; ++kk) acc = fmaf(sT[r][kk], mw2[kk * 32 + c], acc);
        sT[r][32 + c] = fmaxf(acc, 0.f);
    }
    __syncthreads();
    if (tid < 24) {
        const int r = tid / 12, c = tid - 12 * r;
        float acc = mb3[c];
#pragma unroll
        for (int kk = 0; kk < 32; ++kk) acc = fmaf(sT[r][32 + kk], mw3[kk * 12 + c], acc);
        sP[r][c] = acc;
    }
    __syncthreads();
    if (tid < 2) {
        float acc = 0.f;
#pragma unroll
        for (int kk = 0; kk < 12; ++kk) acc = fmaf(sP[tid][kk], sf[kk], acc);
        out[24 + r0 + tid] = acc;
    }
    if (blockIdx.x == 0 && tid < 12) {
        out[tid] = sf[tid];
        out[12 + tid] = 1.0f;
    }
}

extern "C" void kernel_launch(void* const* d_in, const int* in_sizes, int n_in,
                              void* d_out, int out_size, void* d_ws, size_t ws_size,
                              hipStream_t stream) {
    (void)in_sizes; (void)n_in; (void)d_ws; (void)ws_size; (void)out_size;
    const float* pix    = (const float*)d_in[0];
    const float* van_wi = (const float*)d_in[1];
    const float* van_bi = (const float*)d_in[2];
    const float* van_wh = (const float*)d_in[3];
    const float* van_bh = (const float*)d_in[4];
    const float* w1     = (const float*)d_in[5];
    const float* b1     = (const float*)d_in[6];
    const float* w2     = (const float*)d_in[7];
    const float* b2     = (const float*)d_in[8];
    const float* gwi    = (const float*)d_in[9];
    const float* gwh    = (const float*)d_in[10];
    const float* gb     = (const float*)d_in[11];
    const float* mw1    = (const float*)d_in[12];
    const float* mb1    = (const float*)d_in[13];
    const float* mw2    = (const float*)d_in[14];
    const float* mb2    = (const float*)d_in[15];
    const float* mw3    = (const float*)d_in[16];
    const float* mb3    = (const float*)d_in[17];
    const float* sf     = (const float*)d_in[18];
    float* out = (float*)d_out;

    rnn_flag<<<256, 512, 0, stream>>>(
        pix, van_wi, van_bi, van_wh, van_bh,
        w1, b1, w2, b2, gwi, gwh, gb,
        mw1, mb1, mw2, mb2, mw3, mb3, sf, out);
}